// Round 6
// baseline (3039.227 us; speedup 1.0000x reference)
//
#include <hip/hip_runtime.h>
#include <stdint.h>

#define DEV __device__ __forceinline__

// Exact (no-FMA-contraction) squared distance, matching jnp.sum((a-b)**2, axis=-1)
// computed as (dx*dx + dy*dy) + dz*dz with each op rounded.
DEV float d2_exact(float ax, float ay, float az, float bx, float by, float bz) {
    float dx = __fsub_rn(ax, bx);
    float dy = __fsub_rn(ay, by);
    float dz = __fsub_rn(az, bz);
    return __fadd_rn(__fadd_rn(__fmul_rn(dx, dx), __fmul_rn(dy, dy)), __fmul_rn(dz, dz));
}

DEV void atomicMaxF(float* a, float v) {
    if (v >= 0.f) atomicMax((int*)a, __float_as_int(v));
    else          atomicMin((unsigned int*)a, __float_as_uint(v));
}

// ---------------------------------------------------------------------------
// Wave-wide u64 reduction via DPP (VALU ops). Result valid in LANE 63 only.
// ---------------------------------------------------------------------------
template<bool MAXRED>
DEV unsigned long long wave_red_u64_l63(unsigned long long k) {
    unsigned lo = (unsigned)k, hi = (unsigned)(k >> 32);
#define DPP_RED_STEP(ctrl, rmask)                                                          \
    {                                                                                      \
        unsigned nlo = (unsigned)__builtin_amdgcn_update_dpp((int)lo, (int)lo, ctrl,       \
                                                             rmask, 0xF, false);           \
        unsigned nhi = (unsigned)__builtin_amdgcn_update_dpp((int)hi, (int)hi, ctrl,       \
                                                             rmask, 0xF, false);           \
        unsigned long long cur = ((unsigned long long)hi << 32) | lo;                      \
        unsigned long long oth = ((unsigned long long)nhi << 32) | nlo;                    \
        bool take = MAXRED ? (oth > cur) : (oth < cur);                                    \
        lo = take ? nlo : lo;                                                              \
        hi = take ? nhi : hi;                                                              \
    }
    DPP_RED_STEP(0x111, 0xF)  // row_shr:1
    DPP_RED_STEP(0x112, 0xF)  // row_shr:2
    DPP_RED_STEP(0x114, 0xF)  // row_shr:4
    DPP_RED_STEP(0x118, 0xF)  // row_shr:8
    DPP_RED_STEP(0x142, 0xA)  // row_bcast:15 -> rows 1,3
    DPP_RED_STEP(0x143, 0xC)  // row_bcast:31 -> rows 2,3
#undef DPP_RED_STEP
    return ((unsigned long long)hi << 32) | lo;
}

DEV unsigned long long bcast_l63(unsigned long long k) {
    unsigned lo = (unsigned)__builtin_amdgcn_readlane((int)(unsigned)k, 63);
    unsigned hi = (unsigned)__builtin_amdgcn_readlane((int)(unsigned)(k >> 32), 63);
    return ((unsigned long long)hi << 32) | lo;
}

// ---------------------------------------------------------------------------
// FPS with exact spatial pruning. One block per batch.
// - counting-sort points by 4x4x4 Morton cell (once); thread owns a CONTIGUOUS
//   sorted chunk of PPT points -> tight per-thread bbox.
// - per step: lb2(bbox -> c) is an exact f32 lower bound of every d2 in the
//   chunk (monotone rounding, same expression shape as d2_exact). If
//   lb2 >= maxmind for all lanes of a wave, the wave's minds & key can't
//   change -> skip scan, re-post cached key.
// - keys carry ORIGINAL indices (0x7FFFFFFF - idx in low word) so selection
//   (max mind, tie -> min orig idx) is bit-identical to jnp.argmax.
// ---------------------------------------------------------------------------
template<int N, int M, int TPB>
__global__ __launch_bounds__(TPB)
void fps_kernel(const float* __restrict__ pos, float* __restrict__ qpos) {
    const int b = blockIdx.x;
    const float* P = pos + (size_t)b * N * 3;
    float* Q = qpos + (size_t)b * M * 3;
    constexpr int PPT = N / TPB;
    constexpr int NW = TPB / 64;
    __shared__ float sP[N * 3];
    __shared__ int sIdx[N];
    __shared__ int cellCnt[64], cellBase[64];
    __shared__ __align__(16) unsigned long long skey[2][NW];
    const int tid = threadIdx.x;
    const int w = tid >> 6;
    const int lane = tid & 63;

    for (int e = tid; e < N * 3; e += TPB) sP[e] = P[e];
    if (tid < 64) cellCnt[tid] = 0;
    __syncthreads();

    // --- histogram over 64 Morton cells ---
    for (int i = tid; i < N; i += TPB) {
        float x = sP[3 * i], y = sP[3 * i + 1], z = sP[3 * i + 2];
        int cxi = min(3, max(0, (int)(x * 4.f)));
        int cyi = min(3, max(0, (int)(y * 4.f)));
        int czi = min(3, max(0, (int)(z * 4.f)));
        int cell = ((cxi >> 1) << 5) | ((cyi >> 1) << 4) | ((czi >> 1) << 3) |
                   ((cxi & 1) << 2) | ((cyi & 1) << 1) | (czi & 1);
        atomicAdd(&cellCnt[cell], 1);
    }
    __syncthreads();
    if (tid == 0) {
        int acc = 0;
        for (int c = 0; c < 64; c++) { cellBase[c] = acc; acc += cellCnt[c]; cellCnt[c] = 0; }
    }
    __syncthreads();
    // --- scatter sorted order (order within cell arbitrary; exact anyway) ---
    for (int i = tid; i < N; i += TPB) {
        float x = sP[3 * i], y = sP[3 * i + 1], z = sP[3 * i + 2];
        int cxi = min(3, max(0, (int)(x * 4.f)));
        int cyi = min(3, max(0, (int)(y * 4.f)));
        int czi = min(3, max(0, (int)(z * 4.f)));
        int cell = ((cxi >> 1) << 5) | ((cyi >> 1) << 4) | ((czi >> 1) << 3) |
                   ((cxi & 1) << 2) | ((cyi & 1) << 1) | (czi & 1);
        int dst = cellBase[cell] + atomicAdd(&cellCnt[cell], 1);
        sIdx[dst] = i;
    }
    __syncthreads();

    // --- gather contiguous chunk into registers + bbox ---
    float px[PPT], py[PPT], pz[PPT], mind[PPT];
    unsigned lowp[PPT];
    float bxlo, bxhi, bylo, byhi, bzlo, bzhi;
#pragma unroll
    for (int p = 0; p < PPT; p++) {
        int o = sIdx[tid * PPT + p];
        px[p] = sP[3 * o]; py[p] = sP[3 * o + 1]; pz[p] = sP[3 * o + 2];
        mind[p] = __builtin_inff();
        lowp[p] = (unsigned)(0x7FFFFFFF - o);
        if (p == 0) {
            bxlo = bxhi = px[0]; bylo = byhi = py[0]; bzlo = bzhi = pz[0];
        } else {
            bxlo = fminf(bxlo, px[p]); bxhi = fmaxf(bxhi, px[p]);
            bylo = fminf(bylo, py[p]); byhi = fmaxf(byhi, py[p]);
            bzlo = fminf(bzlo, pz[p]); bzhi = fmaxf(bzhi, pz[p]);
        }
    }
    float cx = sP[0], cy = sP[1], cz = sP[2];
    if (tid == 0) { Q[0] = cx; Q[1] = cy; Q[2] = cz; }
    float maxmind = __builtin_inff();
    unsigned long long wlast = 0ull;  // cached post-DPP wave key (valid @ lane63)

    for (int s = 1; s < M; s++) {
        // exact f32 lower bound of d2 for every point in the bbox
        float ax = fmaxf(fmaxf(__fsub_rn(bxlo, cx), __fsub_rn(cx, bxhi)), 0.f);
        float ay = fmaxf(fmaxf(__fsub_rn(bylo, cy), __fsub_rn(cy, byhi)), 0.f);
        float az = fmaxf(fmaxf(__fsub_rn(bzlo, cz), __fsub_rn(cz, bzhi)), 0.f);
        float lb2 = __fadd_rn(__fadd_rn(__fmul_rn(ax, ax), __fmul_rn(ay, ay)),
                              __fmul_rn(az, az));
        bool act = lb2 < maxmind;
        if (__ballot(act) != 0ull) {
            unsigned long long tk = 0ull;
#pragma unroll
            for (int p = 0; p < PPT; p++) {
                float d = d2_exact(px[p], py[p], pz[p], cx, cy, cz);
                float m = fminf(mind[p], d);
                mind[p] = m;
                unsigned long long k =
                    ((unsigned long long)__float_as_uint(m) << 32) | lowp[p];
                tk = (k > tk) ? k : tk;
            }
            maxmind = __uint_as_float((unsigned)(tk >> 32));
            unsigned long long wk = wave_red_u64_l63<true>(tk);
            if (lane == 63) { wlast = wk; skey[s & 1][w] = wk; }
        } else {
            if (lane == 63) skey[s & 1][w] = wlast;
        }
        __syncthreads();
        const ulonglong2* kv = (const ulonglong2*)skey[s & 1];
        unsigned long long kk = 0ull;
#pragma unroll
        for (int i = 0; i < NW / 2; i++) {
            ulonglong2 v = kv[i];
            unsigned long long m = (v.x > v.y) ? v.x : v.y;
            kk = (m > kk) ? m : kk;
        }
        int sel = 0x7FFFFFFF - (int)(unsigned)(kk & 0xFFFFFFFFu);
        cx = sP[3 * sel]; cy = sP[3 * sel + 1]; cz = sP[3 * sel + 2];
        if (tid == 0) { Q[3 * s] = cx; Q[3 * s + 1] = cy; Q[3 * s + 2] = cz; }
    }
}

// ---------------------------------------------------------------------------
// SA1: fused ball-query + PointConv (6 -> 64 -> 64, max-pool) per query-wave.
// One wave handles one (b, radius, query); lane = output feature.
// ---------------------------------------------------------------------------
#define SA1_CAP 1024

__global__ __launch_bounds__(256)
void sa1_kernel(const float* __restrict__ pos, const float* __restrict__ color,
                const float* __restrict__ qpos,
                const float* __restrict__ w1, const float* __restrict__ b1,
                const float* __restrict__ g1, const float* __restrict__ be1,
                const float* __restrict__ w2, const float* __restrict__ b2,
                const float* __restrict__ g2, const float* __restrict__ be2,
                float* __restrict__ x1) {
    __shared__ float candD[4][SA1_CAP];
    __shared__ int   candI[4][SA1_CAP];
    __shared__ int   nbrS[4][64];
    __shared__ __align__(16) float vbuf[4][64][8];
    __shared__ __align__(16) float h1buf[4][64];

    const int lane = threadIdx.x & 63;
    const int w = threadIdx.x >> 6;

    float w1c[6];
#pragma unroll
    for (int i = 0; i < 6; i++) w1c[i] = w1[i * 64 + lane];
    float w2c[64];
#pragma unroll
    for (int i = 0; i < 64; i++) w2c[i] = w2[i * 64 + lane];
    const float rs = rsqrtf(1.0f + 1e-5f);
    const float b1f = b1[lane], s1f = g1[lane] * rs, be1f = be1[lane];
    const float b2f = b2[lane], s2f = g2[lane] * rs, be2f = be2[lane];

    const int gw = blockIdx.x * 4 + w;  // 0..2047

    for (int it = 0; it < 8; ++it) {
        int p = gw * 8 + it;            // 0..16383
        int b = p >> 12;
        int rad = (p >> 11) & 1;
        int q = p & 2047;
        float r2 = (rad == 0) ? (float)(0.2 * 0.2) : (float)(0.1 * 0.1);
        const float* P = pos + (size_t)b * 4096 * 3;
        const float* C = color + (size_t)b * 4096 * 3;
        const float* QP = qpos + ((size_t)b * 2048 + q) * 3;
        float qx = QP[0], qy = QP[1], qz = QP[2];

        // --- ballot-compaction of in-radius candidates ---
        int cnt = 0;
        for (int c0 = 0; c0 < 4096; c0 += 64) {
            int j = c0 + lane;
            float d2 = d2_exact(P[3 * j], P[3 * j + 1], P[3 * j + 2], qx, qy, qz);
            bool pr = (d2 <= r2);
            unsigned long long mk = __ballot(pr);
            int pre = __popcll(mk & ((1ull << lane) - 1ull));
            int dst = cnt + pre;
            if (pr && dst < SA1_CAP) { candD[w][dst] = d2; candI[w][dst] = j; }
            cnt += __popcll(mk);
        }
        __builtin_amdgcn_wave_barrier();

        int nV;
        if (cnt <= 64) {
            nV = cnt;
            if (lane < cnt) nbrS[w][lane] = candI[w][lane];
        } else {
            nV = 64;
            unsigned long long lastK = 0ull;
            if (cnt <= SA1_CAP) {
                for (int k = 0; k < 64; k++) {
                    unsigned long long bk = ~0ull;
                    for (int e = lane; e < cnt; e += 64) {
                        unsigned long long ke =
                            ((unsigned long long)__float_as_uint(candD[w][e]) << 32) |
                            (unsigned)(candI[w][e] + 1);
                        if (ke > lastK && ke < bk) bk = ke;
                    }
                    bk = wave_red_u64_l63<false>(bk);
                    bk = bcast_l63(bk);
                    if (lane == 0) nbrS[w][k] = (int)(unsigned)(bk & 0xFFFFFFFFu) - 1;
                    lastK = bk;
                }
            } else {
                // robust fallback: successor-min over all points, d2 recomputed
                for (int k = 0; k < 64; k++) {
                    unsigned long long bk = ~0ull;
                    for (int j = lane; j < 4096; j += 64) {
                        float d2 = d2_exact(P[3 * j], P[3 * j + 1], P[3 * j + 2], qx, qy, qz);
                        if (d2 <= r2) {
                            unsigned long long ke =
                                ((unsigned long long)__float_as_uint(d2) << 32) | (unsigned)(j + 1);
                            if (ke > lastK && ke < bk) bk = ke;
                        }
                    }
                    bk = wave_red_u64_l63<false>(bk);
                    bk = bcast_l63(bk);
                    if (lane == 0) nbrS[w][k] = (int)(unsigned)(bk & 0xFFFFFFFFu) - 1;
                    lastK = bk;
                }
            }
        }
        __builtin_amdgcn_wave_barrier();

        // --- prefetch neighbor features (color + rel) into LDS ---
        if (lane < nV) {
            int j = nbrS[w][lane];
            vbuf[w][lane][0] = C[3 * j];
            vbuf[w][lane][1] = C[3 * j + 1];
            vbuf[w][lane][2] = C[3 * j + 2];
            vbuf[w][lane][3] = P[3 * j] - qx;
            vbuf[w][lane][4] = P[3 * j + 1] - qy;
            vbuf[w][lane][5] = P[3 * j + 2] - qz;
        }
        __builtin_amdgcn_wave_barrier();

        // --- MLP + max pool ---
        float m = -__builtin_inff();
        for (int n = 0; n < nV; n++) {
            float4 v0 = *reinterpret_cast<const float4*>(&vbuf[w][n][0]);
            float4 v1 = *reinterpret_cast<const float4*>(&vbuf[w][n][4]);
            float h = b1f;
            h = fmaf(v0.x, w1c[0], h); h = fmaf(v0.y, w1c[1], h); h = fmaf(v0.z, w1c[2], h);
            h = fmaf(v0.w, w1c[3], h); h = fmaf(v1.x, w1c[4], h); h = fmaf(v1.y, w1c[5], h);
            h = fmaxf(h, 0.f);
            h = fmaf(h, s1f, be1f);
            h1buf[w][lane] = h;
            __builtin_amdgcn_wave_barrier();
            float a = b2f;
#pragma unroll
            for (int i4 = 0; i4 < 16; i4++) {
                float4 hv = *reinterpret_cast<const float4*>(&h1buf[w][i4 * 4]);
                a = fmaf(hv.x, w2c[4 * i4 + 0], a);
                a = fmaf(hv.y, w2c[4 * i4 + 1], a);
                a = fmaf(hv.z, w2c[4 * i4 + 2], a);
                a = fmaf(hv.w, w2c[4 * i4 + 3], a);
            }
            a = fmaxf(a, 0.f);
            a = fmaf(a, s2f, be2f);
            m = fmaxf(m, a);
            __builtin_amdgcn_wave_barrier();
        }
        x1[((size_t)b * 2048 + q) * 128 + rad * 64 + lane] = (nV > 0) ? m : 0.f;
    }
}

// ---------------------------------------------------------------------------
// SA2 neighbor selection (src = qpos1 [2048], queries = qpos2 [410], 2 radii)
// ---------------------------------------------------------------------------
#define S2CAP 2048

__global__ __launch_bounds__(256)
void sa2sel_kernel(const float* __restrict__ qpos1, const float* __restrict__ qpos2,
                   int* __restrict__ cntOut, int* __restrict__ nbrOut) {
    __shared__ float cD[4][S2CAP];
    __shared__ int   cI[4][S2CAP];
    const int lane = threadIdx.x & 63;
    const int w = threadIdx.x >> 6;
    int p = blockIdx.x * 4 + w;  // 0..3279
    int rad = p & 1;
    int q = (p >> 1) % 410;
    int b = (p >> 1) / 410;
    float r2 = (rad == 0) ? (float)(0.35 * 0.35) : 0.25f;
    const float* S = qpos1 + (size_t)b * 2048 * 3;
    const float* QP = qpos2 + ((size_t)b * 410 + q) * 3;
    float qx = QP[0], qy = QP[1], qz = QP[2];

    int cnt = 0;
    for (int c0 = 0; c0 < 2048; c0 += 64) {
        int j = c0 + lane;
        float d2 = d2_exact(S[3 * j], S[3 * j + 1], S[3 * j + 2], qx, qy, qz);
        bool pr = (d2 <= r2);
        unsigned long long mk = __ballot(pr);
        int pre = __popcll(mk & ((1ull << lane) - 1ull));
        if (pr) { cD[w][cnt + pre] = d2; cI[w][cnt + pre] = j; }
        cnt += __popcll(mk);
    }
    __builtin_amdgcn_wave_barrier();

    int nV = (cnt < 64) ? cnt : 64;
    if (cnt <= 64) {
        if (lane < cnt) nbrOut[(size_t)p * 64 + lane] = cI[w][lane];
    } else {
        unsigned long long lastK = 0ull;
        for (int k = 0; k < 64; k++) {
            unsigned long long bk = ~0ull;
            for (int e = lane; e < cnt; e += 64) {
                unsigned long long ke =
                    ((unsigned long long)__float_as_uint(cD[w][e]) << 32) | (unsigned)(cI[w][e] + 1);
                if (ke > lastK && ke < bk) bk = ke;
            }
            bk = wave_red_u64_l63<false>(bk);
            bk = bcast_l63(bk);
            if (lane == 0) nbrOut[(size_t)p * 64 + k] = (int)(unsigned)(bk & 0xFFFFFFFFu) - 1;
            lastK = bk;
        }
    }
    if (lane == 0) cntOut[p] = nV;
}

// ---------------------------------------------------------------------------
// y = x1 @ W2a[0:128,:] + b2a   (precompute the x-part of SA2 layer 1)
// ---------------------------------------------------------------------------
__global__ __launch_bounds__(256)
void ypre_kernel(const float* __restrict__ x1, const float* __restrict__ w2a,
                 const float* __restrict__ b2a, float* __restrict__ y) {
    __shared__ float xr[4][4][128];
    const int lane = threadIdx.x & 63;
    const int w = threadIdx.x >> 6;
    int r0 = (blockIdx.x * 4 + w) * 4;  // rows 0..8191, 4 per wave
#pragma unroll
    for (int rr = 0; rr < 4; rr++) {
        const float* X = x1 + (size_t)(r0 + rr) * 128;
        xr[w][rr][lane] = X[lane];
        xr[w][rr][lane + 64] = X[lane + 64];
    }
    __builtin_amdgcn_wave_barrier();
    float acc[4][2];
#pragma unroll
    for (int rr = 0; rr < 4; rr++) { acc[rr][0] = b2a[lane]; acc[rr][1] = b2a[lane + 64]; }
    for (int i = 0; i < 128; i++) {
        float w0 = w2a[i * 128 + lane];
        float w1v = w2a[i * 128 + 64 + lane];
#pragma unroll
        for (int rr = 0; rr < 4; rr++) {
            float xv = xr[w][rr][i];
            acc[rr][0] = fmaf(xv, w0, acc[rr][0]);
            acc[rr][1] = fmaf(xv, w1v, acc[rr][1]);
        }
    }
#pragma unroll
    for (int rr = 0; rr < 4; rr++) {
        y[(size_t)(r0 + rr) * 128 + lane] = acc[rr][0];
        y[(size_t)(r0 + rr) * 128 + 64 + lane] = acc[rr][1];
    }
}

// ---------------------------------------------------------------------------
// SA2 PointConv: per (b,q,rad) block: h1 (128) for <=64 neighbors, then
// [64x128]@[128x256] f32 GEMM, ReLU/BN, masked max -> A3 row (520 cols).
// ---------------------------------------------------------------------------
__global__ __launch_bounds__(256)
void sa2gemm_kernel(const float* __restrict__ y, const float* __restrict__ qpos1,
                    const float* __restrict__ qpos2, const float* __restrict__ w2a,
                    const float* __restrict__ g2a, const float* __restrict__ be2a,
                    const float* __restrict__ w2b, const float* __restrict__ b2b,
                    const float* __restrict__ g2b, const float* __restrict__ be2b,
                    const int* __restrict__ cntIn, const int* __restrict__ nbrIn,
                    float* __restrict__ A3) {
    __shared__ __align__(16) float h1T[128][68];
    __shared__ __align__(16) float Bs[16][256];
    __shared__ int nbrS[64];

    const int tid = threadIdx.x;
    const int lane = tid & 63;
    const int w = tid >> 6;
    int p = blockIdx.x;
    int rad = p & 1;
    int q = (p >> 1) % 410;
    int b = (p >> 1) / 410;
    int nV = cntIn[p];
    if (tid < 64) nbrS[tid] = nbrIn[(size_t)p * 64 + tid];
    __syncthreads();

    const float* QP = qpos2 + ((size_t)b * 410 + q) * 3;
    float qx = QP[0], qy = QP[1], qz = QP[2];
    const float rs = rsqrtf(1.0f + 1e-5f);
    float wr0a = w2a[128 * 128 + lane], wr1a = w2a[129 * 128 + lane], wr2a = w2a[130 * 128 + lane];
    float wr0b = w2a[128 * 128 + 64 + lane], wr1b = w2a[129 * 128 + 64 + lane], wr2b = w2a[130 * 128 + 64 + lane];
    float sA = g2a[lane] * rs, beA = be2a[lane];
    float sB = g2a[64 + lane] * rs, beB = be2a[64 + lane];

    for (int n = w; n < 64; n += 4) {
        float v0 = 0.f, v1 = 0.f;
        if (n < nV) {
            int j = nbrS[n];
            const float* Y = y + ((size_t)b * 2048 + j) * 128;
            const float* S = qpos1 + ((size_t)b * 2048 + j) * 3;
            float rx = S[0] - qx, ry = S[1] - qy, rz = S[2] - qz;
            float p0 = Y[lane];
            p0 = fmaf(rx, wr0a, p0); p0 = fmaf(ry, wr1a, p0); p0 = fmaf(rz, wr2a, p0);
            float p1 = Y[64 + lane];
            p1 = fmaf(rx, wr0b, p1); p1 = fmaf(ry, wr1b, p1); p1 = fmaf(rz, wr2b, p1);
            v0 = fmaf(fmaxf(p0, 0.f), sA, beA);
            v1 = fmaf(fmaxf(p1, 0.f), sB, beB);
        }
        h1T[lane][n] = v0;
        h1T[64 + lane][n] = v1;
    }
    __syncthreads();

    const int tn = tid & 7;        // neighbor octet
    const int tf = tid >> 3;       // 0..31 -> 8 output cols each
    float acc[8][8];
#pragma unroll
    for (int r = 0; r < 8; r++)
#pragma unroll
        for (int c = 0; c < 8; c++) acc[r][c] = 0.f;

    for (int kt = 0; kt < 8; kt++) {
        __syncthreads();
#pragma unroll
        for (int i = 0; i < 16; i++) {
            int ee = tid + 256 * i;
            int r = ee >> 8, c = ee & 255;
            Bs[r][c] = w2b[(kt * 16 + r) * 256 + c];
        }
        __syncthreads();
#pragma unroll
        for (int kk = 0; kk < 16; kk++) {
            float4 a0 = *reinterpret_cast<const float4*>(&h1T[kt * 16 + kk][tn * 8]);
            float4 a1 = *reinterpret_cast<const float4*>(&h1T[kt * 16 + kk][tn * 8 + 4]);
            float4 b0 = *reinterpret_cast<const float4*>(&Bs[kk][tf * 8]);
            float4 b1 = *reinterpret_cast<const float4*>(&Bs[kk][tf * 8 + 4]);
            float av[8] = {a0.x, a0.y, a0.z, a0.w, a1.x, a1.y, a1.z, a1.w};
            float bv[8] = {b0.x, b0.y, b0.z, b0.w, b1.x, b1.y, b1.z, b1.w};
#pragma unroll
            for (int r = 0; r < 8; r++)
#pragma unroll
                for (int c = 0; c < 8; c++) acc[r][c] = fmaf(av[r], bv[c], acc[r][c]);
        }
    }

    // epilogue: bias, relu, bn, masked row-max, reduce over neighbor octets
    const int f2 = tf * 8;
    float bb[8], ss[8], beb[8];
#pragma unroll
    for (int c = 0; c < 8; c++) {
        bb[c] = b2b[f2 + c];
        ss[c] = g2b[f2 + c] * rs;
        beb[c] = be2b[f2 + c];
    }
    float mx[8];
#pragma unroll
    for (int c = 0; c < 8; c++) mx[c] = -__builtin_inff();
#pragma unroll
    for (int r = 0; r < 8; r++) {
        int n = tn * 8 + r;
        bool val = (n < nV);
#pragma unroll
        for (int c = 0; c < 8; c++) {
            float h = fmaf(fmaxf(acc[r][c] + bb[c], 0.f), ss[c], beb[c]);
            if (val) mx[c] = fmaxf(mx[c], h);
        }
    }
#pragma unroll
    for (int off = 1; off < 8; off <<= 1) {
#pragma unroll
        for (int c = 0; c < 8; c++) {
            float o = __shfl_xor(mx[c], off);
            mx[c] = fmaxf(mx[c], o);
        }
    }
    if (tn == 0) {
        size_t row3 = (size_t)b * 410 + q;
        float* dst = A3 + row3 * 520 + rad * 256 + f2;
#pragma unroll
        for (int c = 0; c < 8; c++) dst[c] = (nV > 0) ? mx[c] : 0.f;
    }
    if (rad == 0 && tid < 3) {
        A3[((size_t)b * 410 + q) * 520 + 512 + tid] = QP[tid];
    }
}

// ---------------------------------------------------------------------------
// Layer3 GEMM [410x515]@[515x1024] + ReLU/BN + row-max into g[4][1024]
// ---------------------------------------------------------------------------
__global__ __launch_bounds__(256)
void l3_kernel(const float* __restrict__ A3, const float* __restrict__ w3,
               const float* __restrict__ b3, const float* __restrict__ g3,
               const float* __restrict__ be3, float* __restrict__ gout) {
    __shared__ float As[32][17];
    __shared__ float Bs[16][256];
    __shared__ float pm[4][256];
    const int tid = threadIdx.x;
    const int rt = blockIdx.x;   // 0..12
    const int ct = blockIdx.y;   // 0..3
    const int b = blockIdx.z;
    const int rgrp = tid >> 6, li = tid & 63;

    float acc[8][4];
#pragma unroll
    for (int r = 0; r < 8; r++)
#pragma unroll
        for (int j = 0; j < 4; j++) acc[r][j] = 0.f;

    for (int kt = 0; kt < 33; kt++) {
        __syncthreads();
        for (int e = tid; e < 512; e += 256) {
            int r = e >> 4, kk = e & 15;
            int row = rt * 32 + r;
            int k = kt * 16 + kk;
            As[r][kk] = (row < 410 && k < 515) ? A3[((size_t)b * 410 + row) * 520 + k] : 0.f;
        }
        for (int e = tid; e < 4096; e += 256) {
            int r = e >> 8, c = e & 255;
            int k = kt * 16 + r;
            Bs[r][c] = (k < 515) ? w3[(size_t)k * 1024 + ct * 256 + c] : 0.f;
        }
        __syncthreads();
#pragma unroll
        for (int kk = 0; kk < 16; kk++) {
            float bvv[4];
#pragma unroll
            for (int j = 0; j < 4; j++) bvv[j] = Bs[kk][li + 64 * j];
#pragma unroll
            for (int r = 0; r < 8; r++) {
                float av = As[rgrp * 8 + r][kk];
#pragma unroll
                for (int j = 0; j < 4; j++) acc[r][j] = fmaf(av, bvv[j], acc[r][j]);
            }
        }
    }

    const float rs = rsqrtf(1.0f + 1e-5f);
    float mx[4], bb[4], ss[4], beb[4];
#pragma unroll
    for (int j = 0; j < 4; j++) {
        int c = ct * 256 + li + 64 * j;
        bb[j] = b3[c]; ss[j] = g3[c] * rs; beb[j] = be3[c];
        mx[j] = -__builtin_inff();
    }
#pragma unroll
    for (int r = 0; r < 8; r++) {
        int row = rt * 32 + rgrp * 8 + r;
        bool val = (row < 410);
#pragma unroll
        for (int j = 0; j < 4; j++) {
            float h = fmaf(fmaxf(acc[r][j] + bb[j], 0.f), ss[j], beb[j]);
            if (val) mx[j] = fmaxf(mx[j], h);
        }
    }
#pragma unroll
    for (int j = 0; j < 4; j++) pm[rgrp][li + 64 * j] = mx[j];
    __syncthreads();
    if (rgrp == 0) {
#pragma unroll
        for (int j = 0; j < 4; j++) {
            int c = li + 64 * j;
            float v = fmaxf(fmaxf(pm[0][c], pm[1][c]), fmaxf(pm[2][c], pm[3][c]));
            atomicMaxF(&gout[b * 1024 + ct * 256 + c], v);
        }
    }
}

__global__ __launch_bounds__(256)
void initg_kernel(float* g) {
    int i = blockIdx.x * 256 + threadIdx.x;
    if (i < 4096) g[i] = -__builtin_inff();
}

// ---------------------------------------------------------------------------
// Head: relu(g@wl1+bl1) @ wl2 + bl2, L2-normalize rows -> out [4,128]
// ---------------------------------------------------------------------------
__global__ __launch_bounds__(512)
void head_kernel(const float* __restrict__ g, const float* __restrict__ wl1,
                 const float* __restrict__ bl1, const float* __restrict__ wl2,
                 const float* __restrict__ bl2, float* __restrict__ out) {
    __shared__ float gs[1024];
    __shared__ float h1s[512];
    __shared__ float ov[128];
    __shared__ float nrm;
    const int b = blockIdx.x, tid = threadIdx.x;
    gs[tid] = g[b * 1024 + tid];
    gs[tid + 512] = g[b * 1024 + 512 + tid];
    __syncthreads();
    float a = bl1[tid];
#pragma unroll 4
    for (int i = 0; i < 1024; i++) a = fmaf(gs[i], wl1[i * 512 + tid], a);
    h1s[tid] = fmaxf(a, 0.f);
    __syncthreads();
    if (tid < 128) {
        float a2 = bl2[tid];
        for (int i = 0; i < 512; i++) a2 = fmaf(h1s[i], wl2[i * 128 + tid], a2);
        ov[tid] = a2;
    }
    __syncthreads();
    if (tid == 0) {
        float ssum = 0.f;
        for (int i = 0; i < 128; i++) ssum += ov[i] * ov[i];
        nrm = sqrtf(ssum);
    }
    __syncthreads();
    if (tid < 128) out[b * 128 + tid] = ov[tid] / nrm;
}

// ---------------------------------------------------------------------------
extern "C" void kernel_launch(void* const* d_in, const int* in_sizes, int n_in,
                              void* d_out, int out_size, void* d_ws, size_t ws_size,
                              hipStream_t stream) {
    const float* xyz   = (const float*)d_in[0];
    const float* color = (const float*)d_in[1];
    const float* w1a = (const float*)d_in[2];
    const float* b1a = (const float*)d_in[3];
    const float* g1a = (const float*)d_in[4];
    const float* be1a = (const float*)d_in[5];
    const float* w1b = (const float*)d_in[6];
    const float* b1b = (const float*)d_in[7];
    const float* g1b = (const float*)d_in[8];
    const float* be1b = (const float*)d_in[9];
    const float* w2a = (const float*)d_in[10];
    const float* b2a = (const float*)d_in[11];
    const float* g2a = (const float*)d_in[12];
    const float* be2a = (const float*)d_in[13];
    const float* w2b = (const float*)d_in[14];
    const float* b2b = (const float*)d_in[15];
    const float* g2b = (const float*)d_in[16];
    const float* be2b = (const float*)d_in[17];
    const float* w3 = (const float*)d_in[18];
    const float* b3 = (const float*)d_in[19];
    const float* g3 = (const float*)d_in[20];
    const float* be3 = (const float*)d_in[21];
    const float* wl1 = (const float*)d_in[22];
    const float* bl1 = (const float*)d_in[23];
    const float* wl2 = (const float*)d_in[24];
    const float* bl2 = (const float*)d_in[25];
    float* out = (float*)d_out;

    // workspace carve-up (floats)
    float* W = (float*)d_ws;
    float* qpos1 = W;                       // 4*2048*3   = 24576
    float* qpos2 = qpos1 + 24576;           // 4*410*3    = 4920 -> pad 4928
    float* x1    = qpos2 + 4928;            // 4*2048*128 = 1048576
    float* ybuf  = x1 + 1048576;            // 4*2048*128 = 1048576
    float* A3    = ybuf + 1048576;          // 1640*520   = 852800
    float* gbuf  = A3 + 852800;             // 4096
    int* cntBuf  = (int*)(gbuf + 4096);     // 3280
    int* nbrBuf  = cntBuf + 3280;           // 3280*64

    fps_kernel<4096, 2048, 512><<<4, 512, 0, stream>>>(xyz, qpos1);
    fps_kernel<2048, 410, 512><<<4, 512, 0, stream>>>(qpos1, qpos2);
    sa1_kernel<<<512, 256, 0, stream>>>(xyz, color, qpos1,
                                        w1a, b1a, g1a, be1a,
                                        w1b, b1b, g1b, be1b, x1);
    sa2sel_kernel<<<820, 256, 0, stream>>>(qpos1, qpos2, cntBuf, nbrBuf);
    ypre_kernel<<<512, 256, 0, stream>>>(x1, w2a, b2a, ybuf);
    sa2gemm_kernel<<<3280, 256, 0, stream>>>(ybuf, qpos1, qpos2, w2a, g2a, be2a,
                                             w2b, b2b, g2b, be2b, cntBuf, nbrBuf, A3);
    initg_kernel<<<16, 256, 0, stream>>>(gbuf);
    l3_kernel<<<dim3(13, 4, 4), 256, 0, stream>>>(A3, w3, b3, g3, be3, gbuf);
    head_kernel<<<4, 512, 0, stream>>>(gbuf, wl1, bl1, wl2, bl2, out);
}

// Round 8
// 2249.435 us; speedup vs baseline: 1.3511x; 1.3511x over previous
//
#include <hip/hip_runtime.h>
#include <stdint.h>

#define DEV __device__ __forceinline__

// Exact (no-FMA-contraction) squared distance, matching np float32 evaluation:
// (dx*dx + dy*dy) + dz*dz with each op rounded.
DEV float d2_exact(float ax, float ay, float az, float bx, float by, float bz) {
    float dx = __fsub_rn(ax, bx);
    float dy = __fsub_rn(ay, by);
    float dz = __fsub_rn(az, bz);
    return __fadd_rn(__fadd_rn(__fmul_rn(dx, dx), __fmul_rn(dy, dy)), __fmul_rn(dz, dz));
}

DEV void atomicMaxF(float* a, float v) {
    if (v >= 0.f) atomicMax((int*)a, __float_as_int(v));
    else          atomicMin((unsigned int*)a, __float_as_uint(v));
}

// Within-wave LDS producer/consumer fence.
DEV void wave_lds_sync() {
    asm volatile("s_waitcnt lgkmcnt(0)" ::: "memory");
    __builtin_amdgcn_wave_barrier();
}

// ---------------------------------------------------------------------------
// Wave-wide u64 reduction via DPP (VALU ops). Result valid in LANE 63 only.
// ---------------------------------------------------------------------------
template<bool MAXRED>
DEV unsigned long long wave_red_u64_l63(unsigned long long k) {
    unsigned lo = (unsigned)k, hi = (unsigned)(k >> 32);
#define DPP_RED_STEP(ctrl, rmask)                                                          \
    {                                                                                      \
        unsigned nlo = (unsigned)__builtin_amdgcn_update_dpp((int)lo, (int)lo, ctrl,       \
                                                             rmask, 0xF, false);           \
        unsigned nhi = (unsigned)__builtin_amdgcn_update_dpp((int)hi, (int)hi, ctrl,       \
                                                             rmask, 0xF, false);           \
        unsigned long long cur = ((unsigned long long)hi << 32) | lo;                      \
        unsigned long long oth = ((unsigned long long)nhi << 32) | nlo;                    \
        bool take = MAXRED ? (oth > cur) : (oth < cur);                                    \
        lo = take ? nlo : lo;                                                              \
        hi = take ? nhi : hi;                                                              \
    }
    DPP_RED_STEP(0x111, 0xF)  // row_shr:1
    DPP_RED_STEP(0x112, 0xF)  // row_shr:2
    DPP_RED_STEP(0x114, 0xF)  // row_shr:4
    DPP_RED_STEP(0x118, 0xF)  // row_shr:8
    DPP_RED_STEP(0x142, 0xA)  // row_bcast:15 -> rows 1,3
    DPP_RED_STEP(0x143, 0xC)  // row_bcast:31 -> rows 2,3
#undef DPP_RED_STEP
    return ((unsigned long long)hi << 32) | lo;
}

DEV unsigned long long bcast_l63(unsigned long long k) {
    unsigned lo = (unsigned)__builtin_amdgcn_readlane((int)(unsigned)k, 63);
    unsigned hi = (unsigned)__builtin_amdgcn_readlane((int)(unsigned)(k >> 32), 63);
    return ((unsigned long long)hi << 32) | lo;
}

// Inclusive prefix-sum over 64 lanes (canonical gfx9 DPP scan).
DEV int wave_incl_scan_i32(int v) {
    int t;
    t = __builtin_amdgcn_update_dpp(0, v, 0x111, 0xF, 0xF, true);  v += t;
    t = __builtin_amdgcn_update_dpp(0, v, 0x112, 0xF, 0xF, true);  v += t;
    t = __builtin_amdgcn_update_dpp(0, v, 0x114, 0xF, 0xF, true);  v += t;
    t = __builtin_amdgcn_update_dpp(0, v, 0x118, 0xF, 0xF, true);  v += t;
    t = __builtin_amdgcn_update_dpp(0, v, 0x142, 0xA, 0xF, false); v += t;
    t = __builtin_amdgcn_update_dpp(0, v, 0x143, 0xC, 0xF, false); v += t;
    return v;
}

// Wave-wide u32 min, broadcast to all lanes.
DEV unsigned wave_min_u32_bcast(unsigned v) {
    int x = (int)v, t;
#define MINSTEP(ctrl, rmask)                                              \
    t = __builtin_amdgcn_update_dpp(-1, x, ctrl, rmask, 0xF, false);      \
    x = ((unsigned)t < (unsigned)x) ? t : x;
    MINSTEP(0x111, 0xF) MINSTEP(0x112, 0xF) MINSTEP(0x114, 0xF)
    MINSTEP(0x118, 0xF) MINSTEP(0x142, 0xA) MINSTEP(0x143, 0xC)
#undef MINSTEP
    return (unsigned)__builtin_amdgcn_readlane(x, 63);
}

// ---------------------------------------------------------------------------
// Exact top-64-smallest selection by (d2, idx) over cnt (>64) candidates in
// LDS (cD/cI, lane owns slots lane, lane+64, ...). Radix-select on the d2 bit
// pattern (nonneg float -> monotone uint), 8 bits/round, idx tie-break.
// Produces the same SET as 64 iterations of successor-min. Writes 64 indices.
// ---------------------------------------------------------------------------
DEV void topk64_radix(const float* __restrict__ cD, const int* __restrict__ cI,
                      int cnt, int* buckets, int* nbr, int lane) {
    unsigned prefix = 0;    // boundary-value bits above `shift` after each round
    int need = 64;
    int shift;
    int done_le_shift = -1; // if >=0: selected == (db >> done_le_shift) <= prefix
    for (shift = 24; shift >= 0; shift -= 8) {
        for (int i = lane; i < 256; i += 64) buckets[i] = 0;
        wave_lds_sync();
        for (int e = lane; e < cnt; e += 64) {
            unsigned db = __float_as_uint(cD[e]);
            bool match = (shift == 24) || ((db >> (shift + 8)) == prefix);
            if (match) atomicAdd(&buckets[(db >> shift) & 255], 1);
        }
        wave_lds_sync();
        int c0 = buckets[4 * lane + 0], c1 = buckets[4 * lane + 1];
        int c2 = buckets[4 * lane + 2], c3 = buckets[4 * lane + 3];
        int lsum = c0 + c1 + c2 + c3;
        int excl = wave_incl_scan_i32(lsum) - lsum;
        // find boundary bucket B: cum_excl(B) < need <= cum_excl(B)+count(B)
        unsigned packed = 0xFFFFFFFFu;
        int cum = excl;
        int cc[4] = {c0, c1, c2, c3};
#pragma unroll
        for (int j = 0; j < 4; j++) {
            if (cum < need && need <= cum + cc[j])
                packed = ((unsigned)(4 * lane + j) << 20) | (unsigned)cum;
            cum += cc[j];
        }
        unsigned win = wave_min_u32_bcast(packed);
        int B = (int)(win >> 20);
        int bef = (int)(win & 0xFFFFF);
        need -= bef;
        prefix = (shift == 24) ? (unsigned)B : ((prefix << 8) | (unsigned)B);
        int cntB = buckets[B];
        if (cntB == need) { done_le_shift = shift; break; }
    }
    int base = 0;
    if (done_le_shift >= 0) {
        int s = done_le_shift;
        unsigned Pv = prefix;
        for (int e0 = 0; e0 < cnt; e0 += 64) {
            int e = e0 + lane;
            bool sel = false;
            if (e < cnt) sel = ((__float_as_uint(cD[e]) >> s) <= Pv);
            unsigned long long mk = __ballot(sel);
            int pre = __popcll(mk & ((1ull << lane) - 1ull));
            if (sel) nbr[base + pre] = cI[e];
            base += __popcll(mk);
        }
    } else {
        // prefix == exact boundary d2 bits T. All db<T selected, plus `need`
        // smallest-idx among db==T ties (ties >1 essentially never).
        unsigned T = prefix;
        for (int e0 = 0; e0 < cnt; e0 += 64) {
            int e = e0 + lane;
            bool sel = false;
            if (e < cnt) sel = (__float_as_uint(cD[e]) < T);
            unsigned long long mk = __ballot(sel);
            int pre = __popcll(mk & ((1ull << lane) - 1ull));
            if (sel) nbr[base + pre] = cI[e];
            base += __popcll(mk);
        }
        int lastIdx = -1;
        for (int k = 0; k < need; k++) {
            unsigned best = 0xFFFFFFFFu;
            for (int e = lane; e < cnt; e += 64) {
                if (__float_as_uint(cD[e]) == T) {
                    int ix = cI[e];
                    if (ix > lastIdx && (unsigned)ix < best) best = (unsigned)ix;
                }
            }
            best = wave_min_u32_bcast(best);
            if (lane == 0) nbr[base + k] = (int)best;
            lastIdx = (int)best;
        }
    }
}

// ---------------------------------------------------------------------------
// FPS body (round-3 structure: no pruning). One block per batch.
// ---------------------------------------------------------------------------
template<int N, int M, int TPB>
DEV void fps_body(const float* __restrict__ P, float* __restrict__ Q,
                  float* sP, unsigned long long* skey) {
    constexpr int PPT = N / TPB;
    constexpr int NW = TPB / 64;
    const int tid = threadIdx.x;
    const int w = tid >> 6;
    const int lane = tid & 63;

    for (int e = tid; e < N * 3; e += TPB) sP[e] = P[e];
    __syncthreads();

    float px[PPT], py[PPT], pz[PPT], mind[PPT];
#pragma unroll
    for (int p = 0; p < PPT; p++) {
        int i = tid + p * TPB;
        px[p] = sP[3 * i]; py[p] = sP[3 * i + 1]; pz[p] = sP[3 * i + 2];
        mind[p] = __builtin_inff();
    }
    float cx = sP[0], cy = sP[1], cz = sP[2];
    if (tid == 0) { Q[0] = cx; Q[1] = cy; Q[2] = cz; }

    for (int s = 1; s < M; s++) {
        float bestm = -1.f;
        int bidx = 0;
#pragma unroll
        for (int p = 0; p < PPT; p++) {
            float d = d2_exact(px[p], py[p], pz[p], cx, cy, cz);
            float m = fminf(mind[p], d);
            mind[p] = m;
            if (m > bestm) { bestm = m; bidx = tid + p * TPB; }  // strict > keeps smallest idx
        }
        unsigned long long key =
            ((unsigned long long)__float_as_uint(bestm) << 32) | (unsigned)(0x7FFFFFFF - bidx);
        key = wave_red_u64_l63<true>(key);
        if (lane == 63) skey[(s & 1) * NW + w] = key;
        __syncthreads();
        const ulonglong2* kv = (const ulonglong2*)(skey + (s & 1) * NW);
        unsigned long long kk = 0ull;
#pragma unroll
        for (int i = 0; i < NW / 2; i++) {
            ulonglong2 v = kv[i];
            unsigned long long m2 = (v.x > v.y) ? v.x : v.y;
            kk = (m2 > kk) ? m2 : kk;
        }
        int sel = 0x7FFFFFFF - (int)(unsigned)(kk & 0xFFFFFFFFu);
        cx = sP[3 * sel]; cy = sP[3 * sel + 1]; cz = sP[3 * sel + 2];
        if (tid == 0) { Q[3 * s] = cx; Q[3 * s + 1] = cy; Q[3 * s + 2] = cz; }
    }
}

__global__ __launch_bounds__(256)
void fps1_kernel(const float* __restrict__ pos, float* __restrict__ qpos) {
    __shared__ float sP[4096 * 3];
    __shared__ __align__(16) unsigned long long skey[2 * 4];
    const int b = blockIdx.x;
    fps_body<4096, 2048, 256>(pos + (size_t)b * 4096 * 3, qpos + (size_t)b * 2048 * 3, sP, skey);
}

// ---------------------------------------------------------------------------
// Fused: blocks 0..3 = FPS2 (qpos1 -> qpos2), blocks 4..515 = SA1.
// Both depend only on fps1's qpos1, so fps2 hides under sa1.
// ---------------------------------------------------------------------------
#define SA1_CAP 1024

struct Sa1Lds {
    float candD[4][SA1_CAP];
    int   candI[4][SA1_CAP];
    int   nbrS[4][64];
    int   buckets[4][256];
    float vbuf[4][64][8];     // offset 37888, 16B aligned
    float h1buf[4][64];       // offset 46080, 16B aligned
};
struct Fps2Lds {
    float sP[2048 * 3];
    unsigned long long skey[2 * 4];
};
union Sa1FusedLds { Sa1Lds sa; Fps2Lds fps; };

__global__ __launch_bounds__(256)
void sa1_fps2_kernel(const float* __restrict__ pos, const float* __restrict__ color,
                     const float* __restrict__ qpos1, float* __restrict__ qpos2,
                     const float* __restrict__ w1, const float* __restrict__ b1,
                     const float* __restrict__ g1, const float* __restrict__ be1,
                     const float* __restrict__ w2, const float* __restrict__ b2,
                     const float* __restrict__ g2, const float* __restrict__ be2,
                     float* __restrict__ x1) {
    __shared__ __align__(16) Sa1FusedLds u;

    if (blockIdx.x < 4) {
        const int b = blockIdx.x;
        fps_body<2048, 410, 256>(qpos1 + (size_t)b * 2048 * 3, qpos2 + (size_t)b * 410 * 3,
                                 u.fps.sP, u.fps.skey);
        return;
    }

    const int lane = threadIdx.x & 63;
    const int w = threadIdx.x >> 6;

    float w1c[6];
#pragma unroll
    for (int i = 0; i < 6; i++) w1c[i] = w1[i * 64 + lane];
    float w2c[64];
#pragma unroll
    for (int i = 0; i < 64; i++) w2c[i] = w2[i * 64 + lane];
    const float rs = rsqrtf(1.0f + 1e-5f);
    const float b1f = b1[lane], s1f = g1[lane] * rs, be1f = be1[lane];
    const float b2f = b2[lane], s2f = g2[lane] * rs, be2f = be2[lane];

    const int gw = (blockIdx.x - 4) * 4 + w;  // 0..2047

    for (int it = 0; it < 8; ++it) {
        int p = gw * 8 + it;            // 0..16383
        int b = p >> 12;
        int rad = (p >> 11) & 1;
        int q = p & 2047;
        float r2 = (rad == 0) ? (float)(0.2 * 0.2) : (float)(0.1 * 0.1);
        const float* P = pos + (size_t)b * 4096 * 3;
        const float* C = color + (size_t)b * 4096 * 3;
        const float* QP = qpos1 + ((size_t)b * 2048 + q) * 3;
        float qx = QP[0], qy = QP[1], qz = QP[2];

        // --- ballot-compaction of in-radius candidates ---
        int cnt = 0;
        for (int c0 = 0; c0 < 4096; c0 += 64) {
            int j = c0 + lane;
            float d2 = d2_exact(P[3 * j], P[3 * j + 1], P[3 * j + 2], qx, qy, qz);
            bool pr = (d2 <= r2);
            unsigned long long mk = __ballot(pr);
            int pre = __popcll(mk & ((1ull << lane) - 1ull));
            int dst = cnt + pre;
            if (pr && dst < SA1_CAP) { u.sa.candD[w][dst] = d2; u.sa.candI[w][dst] = j; }
            cnt += __popcll(mk);
        }
        wave_lds_sync();

        int nV;
        if (cnt <= 64) {
            nV = cnt;
            if (lane < cnt) u.sa.nbrS[w][lane] = u.sa.candI[w][lane];
        } else {
            nV = 64;
            if (cnt <= SA1_CAP) {
                topk64_radix(u.sa.candD[w], u.sa.candI[w], cnt,
                             u.sa.buckets[w], u.sa.nbrS[w], lane);
            } else {
                // robust fallback: serial successor-min over all points (rare)
                unsigned long long lastK = 0ull;
                for (int k = 0; k < 64; k++) {
                    unsigned long long bk = ~0ull;
                    for (int j = lane; j < 4096; j += 64) {
                        float d2 = d2_exact(P[3 * j], P[3 * j + 1], P[3 * j + 2], qx, qy, qz);
                        if (d2 <= r2) {
                            unsigned long long ke =
                                ((unsigned long long)__float_as_uint(d2) << 32) | (unsigned)(j + 1);
                            if (ke > lastK && ke < bk) bk = ke;
                        }
                    }
                    bk = wave_red_u64_l63<false>(bk);
                    bk = bcast_l63(bk);
                    if (lane == 0) u.sa.nbrS[w][k] = (int)(unsigned)(bk & 0xFFFFFFFFu) - 1;
                    lastK = bk;
                }
            }
        }
        wave_lds_sync();

        // --- prefetch neighbor features (color + rel) into LDS ---
        if (lane < nV) {
            int j = u.sa.nbrS[w][lane];
            u.sa.vbuf[w][lane][0] = C[3 * j];
            u.sa.vbuf[w][lane][1] = C[3 * j + 1];
            u.sa.vbuf[w][lane][2] = C[3 * j + 2];
            u.sa.vbuf[w][lane][3] = P[3 * j] - qx;
            u.sa.vbuf[w][lane][4] = P[3 * j + 1] - qy;
            u.sa.vbuf[w][lane][5] = P[3 * j + 2] - qz;
        }
        wave_lds_sync();

        // --- MLP + max pool ---
        float m = -__builtin_inff();
        for (int n = 0; n < nV; n++) {
            float4 v0 = *reinterpret_cast<const float4*>(&u.sa.vbuf[w][n][0]);
            float4 v1 = *reinterpret_cast<const float4*>(&u.sa.vbuf[w][n][4]);
            float h = b1f;
            h = fmaf(v0.x, w1c[0], h); h = fmaf(v0.y, w1c[1], h); h = fmaf(v0.z, w1c[2], h);
            h = fmaf(v0.w, w1c[3], h); h = fmaf(v1.x, w1c[4], h); h = fmaf(v1.y, w1c[5], h);
            h = fmaxf(h, 0.f);
            h = fmaf(h, s1f, be1f);
            u.sa.h1buf[w][lane] = h;
            wave_lds_sync();
            float a = b2f;
#pragma unroll
            for (int i4 = 0; i4 < 16; i4++) {
                float4 hv = *reinterpret_cast<const float4*>(&u.sa.h1buf[w][i4 * 4]);
                a = fmaf(hv.x, w2c[4 * i4 + 0], a);
                a = fmaf(hv.y, w2c[4 * i4 + 1], a);
                a = fmaf(hv.z, w2c[4 * i4 + 2], a);
                a = fmaf(hv.w, w2c[4 * i4 + 3], a);
            }
            a = fmaxf(a, 0.f);
            a = fmaf(a, s2f, be2f);
            m = fmaxf(m, a);
            __builtin_amdgcn_wave_barrier();
        }
        x1[((size_t)b * 2048 + q) * 128 + rad * 64 + lane] = (nV > 0) ? m : 0.f;
    }
}

// ---------------------------------------------------------------------------
// Fused: blocks 0..819 = SA2 neighbor selection; blocks 820..1331 = ypre.
// (independent: sa2sel needs qpos2, ypre needs x1)
// ---------------------------------------------------------------------------
struct S2Lds {
    float cD[4][2048];
    int   cI[4][2048];
    int   buckets[4][256];
};
struct YpreLds { float xr[4][4][128]; };
union S2FusedLds { S2Lds s2; YpreLds yp; };

__global__ __launch_bounds__(256)
void sa2sel_ypre_kernel(const float* __restrict__ qpos1, const float* __restrict__ qpos2,
                        int* __restrict__ cntOut, int* __restrict__ nbrOut,
                        const float* __restrict__ x1, const float* __restrict__ w2a,
                        const float* __restrict__ b2a, float* __restrict__ y) {
    __shared__ __align__(16) S2FusedLds u;
    const int lane = threadIdx.x & 63;
    const int w = threadIdx.x >> 6;

    if (blockIdx.x >= 820) {
        // ---- ypre ----
        int r0 = ((blockIdx.x - 820) * 4 + w) * 4;  // rows 0..8191, 4 per wave
#pragma unroll
        for (int rr = 0; rr < 4; rr++) {
            const float* X = x1 + (size_t)(r0 + rr) * 128;
            u.yp.xr[w][rr][lane] = X[lane];
            u.yp.xr[w][rr][lane + 64] = X[lane + 64];
        }
        wave_lds_sync();
        float acc[4][2];
#pragma unroll
        for (int rr = 0; rr < 4; rr++) { acc[rr][0] = b2a[lane]; acc[rr][1] = b2a[lane + 64]; }
        for (int i = 0; i < 128; i++) {
            float w0 = w2a[i * 128 + lane];
            float w1v = w2a[i * 128 + 64 + lane];
#pragma unroll
            for (int rr = 0; rr < 4; rr++) {
                float xv = u.yp.xr[w][rr][i];
                acc[rr][0] = fmaf(xv, w0, acc[rr][0]);
                acc[rr][1] = fmaf(xv, w1v, acc[rr][1]);
            }
        }
#pragma unroll
        for (int rr = 0; rr < 4; rr++) {
            y[(size_t)(r0 + rr) * 128 + lane] = acc[rr][0];
            y[(size_t)(r0 + rr) * 128 + 64 + lane] = acc[rr][1];
        }
        return;
    }

    // ---- sa2sel ----
    int p = blockIdx.x * 4 + w;  // 0..3279
    int rad = p & 1;
    int q = (p >> 1) % 410;
    int b = (p >> 1) / 410;
    float r2 = (rad == 0) ? (float)(0.35 * 0.35) : 0.25f;
    const float* S = qpos1 + (size_t)b * 2048 * 3;
    const float* QP = qpos2 + ((size_t)b * 410 + q) * 3;
    float qx = QP[0], qy = QP[1], qz = QP[2];

    int cnt = 0;
    for (int c0 = 0; c0 < 2048; c0 += 64) {
        int j = c0 + lane;
        float d2 = d2_exact(S[3 * j], S[3 * j + 1], S[3 * j + 2], qx, qy, qz);
        bool pr = (d2 <= r2);
        unsigned long long mk = __ballot(pr);
        int pre = __popcll(mk & ((1ull << lane) - 1ull));
        if (pr) { u.s2.cD[w][cnt + pre] = d2; u.s2.cI[w][cnt + pre] = j; }
        cnt += __popcll(mk);
    }
    wave_lds_sync();

    int nV = (cnt < 64) ? cnt : 64;
    if (cnt <= 64) {
        if (lane < cnt) nbrOut[(size_t)p * 64 + lane] = u.s2.cI[w][lane];
    } else {
        topk64_radix(u.s2.cD[w], u.s2.cI[w], cnt,
                     u.s2.buckets[w], nbrOut + (size_t)p * 64, lane);
    }
    if (lane == 0) cntOut[p] = nV;
}

// ---------------------------------------------------------------------------
// SA2 PointConv: per (b,q,rad) block: h1 (128) for <=64 neighbors, then
// [64x128]@[128x256] f32 GEMM, ReLU/BN, masked max -> A3 row (520 cols).
// ---------------------------------------------------------------------------
__global__ __launch_bounds__(256)
void sa2gemm_kernel(const float* __restrict__ y, const float* __restrict__ qpos1,
                    const float* __restrict__ qpos2, const float* __restrict__ w2a,
                    const float* __restrict__ g2a, const float* __restrict__ be2a,
                    const float* __restrict__ w2b, const float* __restrict__ b2b,
                    const float* __restrict__ g2b, const float* __restrict__ be2b,
                    const int* __restrict__ cntIn, const int* __restrict__ nbrIn,
                    float* __restrict__ A3) {
    __shared__ __align__(16) float h1T[128][68];
    __shared__ __align__(16) float Bs[16][256];
    __shared__ int nbrS[64];

    const int tid = threadIdx.x;
    const int lane = tid & 63;
    const int w = tid >> 6;
    int p = blockIdx.x;
    int rad = p & 1;
    int q = (p >> 1) % 410;
    int b = (p >> 1) / 410;
    int nV = cntIn[p];
    if (tid < 64) nbrS[tid] = nbrIn[(size_t)p * 64 + tid];
    __syncthreads();

    const float* QP = qpos2 + ((size_t)b * 410 + q) * 3;
    float qx = QP[0], qy = QP[1], qz = QP[2];
    const float rs = rsqrtf(1.0f + 1e-5f);
    float wr0a = w2a[128 * 128 + lane], wr1a = w2a[129 * 128 + lane], wr2a = w2a[130 * 128 + lane];
    float wr0b = w2a[128 * 128 + 64 + lane], wr1b = w2a[129 * 128 + 64 + lane], wr2b = w2a[130 * 128 + 64 + lane];
    float sA = g2a[lane] * rs, beA = be2a[lane];
    float sB = g2a[64 + lane] * rs, beB = be2a[64 + lane];

    for (int n = w; n < 64; n += 4) {
        float v0 = 0.f, v1 = 0.f;
        if (n < nV) {
            int j = nbrS[n];
            const float* Y = y + ((size_t)b * 2048 + j) * 128;
            const float* S = qpos1 + ((size_t)b * 2048 + j) * 3;
            float rx = S[0] - qx, ry = S[1] - qy, rz = S[2] - qz;
            float p0 = Y[lane];
            p0 = fmaf(rx, wr0a, p0); p0 = fmaf(ry, wr1a, p0); p0 = fmaf(rz, wr2a, p0);
            float p1 = Y[64 + lane];
            p1 = fmaf(rx, wr0b, p1); p1 = fmaf(ry, wr1b, p1); p1 = fmaf(rz, wr2b, p1);
            v0 = fmaf(fmaxf(p0, 0.f), sA, beA);
            v1 = fmaf(fmaxf(p1, 0.f), sB, beB);
        }
        h1T[lane][n] = v0;
        h1T[64 + lane][n] = v1;
    }
    __syncthreads();

    const int tn = tid & 7;        // neighbor octet
    const int tf = tid >> 3;       // 0..31 -> 8 output cols each
    float acc[8][8];
#pragma unroll
    for (int r = 0; r < 8; r++)
#pragma unroll
        for (int c = 0; c < 8; c++) acc[r][c] = 0.f;

    for (int kt = 0; kt < 8; kt++) {
        __syncthreads();
#pragma unroll
        for (int i = 0; i < 16; i++) {
            int ee = tid + 256 * i;
            int r = ee >> 8, c = ee & 255;
            Bs[r][c] = w2b[(kt * 16 + r) * 256 + c];
        }
        __syncthreads();
#pragma unroll
        for (int kk = 0; kk < 16; kk++) {
            float4 a0 = *reinterpret_cast<const float4*>(&h1T[kt * 16 + kk][tn * 8]);
            float4 a1 = *reinterpret_cast<const float4*>(&h1T[kt * 16 + kk][tn * 8 + 4]);
            float4 b0 = *reinterpret_cast<const float4*>(&Bs[kk][tf * 8]);
            float4 b1 = *reinterpret_cast<const float4*>(&Bs[kk][tf * 8 + 4]);
            float av[8] = {a0.x, a0.y, a0.z, a0.w, a1.x, a1.y, a1.z, a1.w};
            float bv[8] = {b0.x, b0.y, b0.z, b0.w, b1.x, b1.y, b1.z, b1.w};
#pragma unroll
            for (int r = 0; r < 8; r++)
#pragma unroll
                for (int c = 0; c < 8; c++) acc[r][c] = fmaf(av[r], bv[c], acc[r][c]);
        }
    }

    const int f2 = tf * 8;
    float bb[8], ss[8], beb[8];
#pragma unroll
    for (int c = 0; c < 8; c++) {
        bb[c] = b2b[f2 + c];
        ss[c] = g2b[f2 + c] * rs;
        beb[c] = be2b[f2 + c];
    }
    float mx[8];
#pragma unroll
    for (int c = 0; c < 8; c++) mx[c] = -__builtin_inff();
#pragma unroll
    for (int r = 0; r < 8; r++) {
        int n = tn * 8 + r;
        bool val = (n < nV);
#pragma unroll
        for (int c = 0; c < 8; c++) {
            float h = fmaf(fmaxf(acc[r][c] + bb[c], 0.f), ss[c], beb[c]);
            if (val) mx[c] = fmaxf(mx[c], h);
        }
    }
#pragma unroll
    for (int off = 1; off < 8; off <<= 1) {
#pragma unroll
        for (int c = 0; c < 8; c++) {
            float o = __shfl_xor(mx[c], off);
            mx[c] = fmaxf(mx[c], o);
        }
    }
    if (tn == 0) {
        size_t row3 = (size_t)b * 410 + q;
        float* dst = A3 + row3 * 520 + rad * 256 + f2;
#pragma unroll
        for (int c = 0; c < 8; c++) dst[c] = (nV > 0) ? mx[c] : 0.f;
    }
    if (rad == 0 && tid < 3) {
        A3[((size_t)b * 410 + q) * 520 + 512 + tid] = QP[tid];
    }
}

// ---------------------------------------------------------------------------
// Layer3 GEMM [410x515]@[515x1024] + ReLU/BN + row-max into g[4][1024]
// ---------------------------------------------------------------------------
__global__ __launch_bounds__(256)
void l3_kernel(const float* __restrict__ A3, const float* __restrict__ w3,
               const float* __restrict__ b3, const float* __restrict__ g3,
               const float* __restrict__ be3, float* __restrict__ gout) {
    __shared__ float As[32][17];
    __shared__ float Bs[16][256];
    __shared__ float pm[4][256];
    const int tid = threadIdx.x;
    const int rt = blockIdx.x;   // 0..12
    const int ct = blockIdx.y;   // 0..3
    const int b = blockIdx.z;
    const int rgrp = tid >> 6, li = tid & 63;

    float acc[8][4];
#pragma unroll
    for (int r = 0; r < 8; r++)
#pragma unroll
        for (int j = 0; j < 4; j++) acc[r][j] = 0.f;

    for (int kt = 0; kt < 33; kt++) {
        __syncthreads();
        for (int e = tid; e < 512; e += 256) {
            int r = e >> 4, kk = e & 15;
            int row = rt * 32 + r;
            int k = kt * 16 + kk;
            As[r][kk] = (row < 410 && k < 515) ? A3[((size_t)b * 410 + row) * 520 + k] : 0.f;
        }
        for (int e = tid; e < 4096; e += 256) {
            int r = e >> 8, c = e & 255;
            int k = kt * 16 + r;
            Bs[r][c] = (k < 515) ? w3[(size_t)k * 1024 + ct * 256 + c] : 0.f;
        }
        __syncthreads();
#pragma unroll
        for (int kk = 0; kk < 16; kk++) {
            float bvv[4];
#pragma unroll
            for (int j = 0; j < 4; j++) bvv[j] = Bs[kk][li + 64 * j];
#pragma unroll
            for (int r = 0; r < 8; r++) {
                float av = As[rgrp * 8 + r][kk];
#pragma unroll
                for (int j = 0; j < 4; j++) acc[r][j] = fmaf(av, bvv[j], acc[r][j]);
            }
        }
    }

    const float rs = rsqrtf(1.0f + 1e-5f);
    float mx[4], bb[4], ss[4], beb[4];
#pragma unroll
    for (int j = 0; j < 4; j++) {
        int c = ct * 256 + li + 64 * j;
        bb[j] = b3[c]; ss[j] = g3[c] * rs; beb[j] = be3[c];
        mx[j] = -__builtin_inff();
    }
#pragma unroll
    for (int r = 0; r < 8; r++) {
        int row = rt * 32 + rgrp * 8 + r;
        bool val = (row < 410);
#pragma unroll
        for (int j = 0; j < 4; j++) {
            float h = fmaf(fmaxf(acc[r][j] + bb[j], 0.f), ss[j], beb[j]);
            if (val) mx[j] = fmaxf(mx[j], h);
        }
    }
#pragma unroll
    for (int j = 0; j < 4; j++) pm[rgrp][li + 64 * j] = mx[j];
    __syncthreads();
    if (rgrp == 0) {
#pragma unroll
        for (int j = 0; j < 4; j++) {
            int c = li + 64 * j;
            float v = fmaxf(fmaxf(pm[0][c], pm[1][c]), fmaxf(pm[2][c], pm[3][c]));
            atomicMaxF(&gout[b * 1024 + ct * 256 + c], v);
        }
    }
}

__global__ __launch_bounds__(256)
void initg_kernel(float* g) {
    int i = blockIdx.x * 256 + threadIdx.x;
    if (i < 4096) g[i] = -__builtin_inff();
}

// ---------------------------------------------------------------------------
// Head: relu(g@wl1+bl1) @ wl2 + bl2, L2-normalize rows -> out [4,128]
// ---------------------------------------------------------------------------
__global__ __launch_bounds__(512)
void head_kernel(const float* __restrict__ g, const float* __restrict__ wl1,
                 const float* __restrict__ bl1, const float* __restrict__ wl2,
                 const float* __restrict__ bl2, float* __restrict__ out) {
    __shared__ float gs[1024];
    __shared__ float h1s[512];
    __shared__ float ov[128];
    __shared__ float nrm;
    const int b = blockIdx.x, tid = threadIdx.x;
    gs[tid] = g[b * 1024 + tid];
    gs[tid + 512] = g[b * 1024 + 512 + tid];
    __syncthreads();
    float a = bl1[tid];
#pragma unroll 4
    for (int i = 0; i < 1024; i++) a = fmaf(gs[i], wl1[i * 512 + tid], a);
    h1s[tid] = fmaxf(a, 0.f);
    __syncthreads();
    if (tid < 128) {
        float a2 = bl2[tid];
        for (int i = 0; i < 512; i++) a2 = fmaf(h1s[i], wl2[i * 128 + tid], a2);
        ov[tid] = a2;
    }
    __syncthreads();
    if (tid == 0) {
        float ssum = 0.f;
        for (int i = 0; i < 128; i++) ssum += ov[i] * ov[i];
        nrm = sqrtf(ssum);
    }
    __syncthreads();
    if (tid < 128) out[b * 128 + tid] = ov[tid] / nrm;
}

// ---------------------------------------------------------------------------
extern "C" void kernel_launch(void* const* d_in, const int* in_sizes, int n_in,
                              void* d_out, int out_size, void* d_ws, size_t ws_size,
                              hipStream_t stream) {
    const float* xyz   = (const float*)d_in[0];
    const float* color = (const float*)d_in[1];
    const float* w1a = (const float*)d_in[2];
    const float* b1a = (const float*)d_in[3];
    const float* g1a = (const float*)d_in[4];
    const float* be1a = (const float*)d_in[5];
    const float* w1b = (const float*)d_in[6];
    const float* b1b = (const float*)d_in[7];
    const float* g1b = (const float*)d_in[8];
    const float* be1b = (const float*)d_in[9];
    const float* w2a = (const float*)d_in[10];
    const float* b2a = (const float*)d_in[11];
    const float* g2a = (const float*)d_in[12];
    const float* be2a = (const float*)d_in[13];
    const float* w2b = (const float*)d_in[14];
    const float* b2b = (const float*)d_in[15];
    const float* g2b = (const float*)d_in[16];
    const float* be2b = (const float*)d_in[17];
    const float* w3 = (const float*)d_in[18];
    const float* b3 = (const float*)d_in[19];
    const float* g3 = (const float*)d_in[20];
    const float* be3 = (const float*)d_in[21];
    const float* wl1 = (const float*)d_in[22];
    const float* bl1 = (const float*)d_in[23];
    const float* wl2 = (const float*)d_in[24];
    const float* bl2 = (const float*)d_in[25];
    float* out = (float*)d_out;

    // workspace carve-up (floats)
    float* W = (float*)d_ws;
    float* qpos1 = W;                       // 4*2048*3   = 24576
    float* qpos2 = qpos1 + 24576;           // 4*410*3    = 4920 -> pad 4928
    float* x1    = qpos2 + 4928;            // 4*2048*128 = 1048576
    float* ybuf  = x1 + 1048576;            // 4*2048*128 = 1048576
    float* A3    = ybuf + 1048576;          // 1640*520   = 852800
    float* gbuf  = A3 + 852800;             // 4096
    int* cntBuf  = (int*)(gbuf + 4096);     // 3280
    int* nbrBuf  = cntBuf + 3280;           // 3280*64

    fps1_kernel<<<4, 256, 0, stream>>>(xyz, qpos1);
    sa1_fps2_kernel<<<516, 256, 0, stream>>>(xyz, color, qpos1, qpos2,
                                             w1a, b1a, g1a, be1a,
                                             w1b, b1b, g1b, be1b, x1);
    sa2sel_ypre_kernel<<<1332, 256, 0, stream>>>(qpos1, qpos2, cntBuf, nbrBuf,
                                                 x1, w2a, b2a, ybuf);
    sa2gemm_kernel<<<3280, 256, 0, stream>>>(ybuf, qpos1, qpos2, w2a, g2a, be2a,
                                             w2b, b2b, g2b, be2b, cntBuf, nbrBuf, A3);
    initg_kernel<<<16, 256, 0, stream>>>(gbuf);
    l3_kernel<<<dim3(13, 4, 4), 256, 0, stream>>>(A3, w3, b3, g3, be3, gbuf);
    head_kernel<<<4, 512, 0, stream>>>(gbuf, wl1, bl1, wl2, bl2, out);
}

// Round 9
// 2081.074 us; speedup vs baseline: 1.4604x; 1.0809x over previous
//
#include <hip/hip_runtime.h>
#include <stdint.h>

#define DEV __device__ __forceinline__

// Exact (no-FMA-contraction) squared distance, matching np float32 evaluation:
// (dx*dx + dy*dy) + dz*dz with each op rounded.
DEV float d2_exact(float ax, float ay, float az, float bx, float by, float bz) {
    float dx = __fsub_rn(ax, bx);
    float dy = __fsub_rn(ay, by);
    float dz = __fsub_rn(az, bz);
    return __fadd_rn(__fadd_rn(__fmul_rn(dx, dx), __fmul_rn(dy, dy)), __fmul_rn(dz, dz));
}

DEV void atomicMaxF(float* a, float v) {
    if (v >= 0.f) atomicMax((int*)a, __float_as_int(v));
    else          atomicMin((unsigned int*)a, __float_as_uint(v));
}

// Within-wave LDS producer/consumer fence.
DEV void wave_lds_sync() {
    asm volatile("s_waitcnt lgkmcnt(0)" ::: "memory");
    __builtin_amdgcn_wave_barrier();
}

// Spin until *p >= need (device-scope coherent RMW polling), then acquire.
DEV void wait_prog(int* p, int need) {
    if ((threadIdx.x & 63) == 0) {
        while (atomicAdd(p, 0) < need) __builtin_amdgcn_s_sleep(32);
    }
    __builtin_amdgcn_wave_barrier();
    __threadfence();  // acquire: invalidate caches before reading produced data
}

// ---------------------------------------------------------------------------
// Wave-wide u64 reduction via DPP (VALU ops). Result valid in LANE 63 only.
// ---------------------------------------------------------------------------
template<bool MAXRED>
DEV unsigned long long wave_red_u64_l63(unsigned long long k) {
    unsigned lo = (unsigned)k, hi = (unsigned)(k >> 32);
#define DPP_RED_STEP(ctrl, rmask)                                                          \
    {                                                                                      \
        unsigned nlo = (unsigned)__builtin_amdgcn_update_dpp((int)lo, (int)lo, ctrl,       \
                                                             rmask, 0xF, false);           \
        unsigned nhi = (unsigned)__builtin_amdgcn_update_dpp((int)hi, (int)hi, ctrl,       \
                                                             rmask, 0xF, false);           \
        unsigned long long cur = ((unsigned long long)hi << 32) | lo;                      \
        unsigned long long oth = ((unsigned long long)nhi << 32) | nlo;                    \
        bool take = MAXRED ? (oth > cur) : (oth < cur);                                    \
        lo = take ? nlo : lo;                                                              \
        hi = take ? nhi : hi;                                                              \
    }
    DPP_RED_STEP(0x111, 0xF)  // row_shr:1
    DPP_RED_STEP(0x112, 0xF)  // row_shr:2
    DPP_RED_STEP(0x114, 0xF)  // row_shr:4
    DPP_RED_STEP(0x118, 0xF)  // row_shr:8
    DPP_RED_STEP(0x142, 0xA)  // row_bcast:15 -> rows 1,3
    DPP_RED_STEP(0x143, 0xC)  // row_bcast:31 -> rows 2,3
#undef DPP_RED_STEP
    return ((unsigned long long)hi << 32) | lo;
}

DEV unsigned long long bcast_l63(unsigned long long k) {
    unsigned lo = (unsigned)__builtin_amdgcn_readlane((int)(unsigned)k, 63);
    unsigned hi = (unsigned)__builtin_amdgcn_readlane((int)(unsigned)(k >> 32), 63);
    return ((unsigned long long)hi << 32) | lo;
}

// Inclusive prefix-sum over 64 lanes (canonical gfx9 DPP scan).
DEV int wave_incl_scan_i32(int v) {
    int t;
    t = __builtin_amdgcn_update_dpp(0, v, 0x111, 0xF, 0xF, true);  v += t;
    t = __builtin_amdgcn_update_dpp(0, v, 0x112, 0xF, 0xF, true);  v += t;
    t = __builtin_amdgcn_update_dpp(0, v, 0x114, 0xF, 0xF, true);  v += t;
    t = __builtin_amdgcn_update_dpp(0, v, 0x118, 0xF, 0xF, true);  v += t;
    t = __builtin_amdgcn_update_dpp(0, v, 0x142, 0xA, 0xF, false); v += t;
    t = __builtin_amdgcn_update_dpp(0, v, 0x143, 0xC, 0xF, false); v += t;
    return v;
}

// Wave-wide u32 min, broadcast to all lanes.
DEV unsigned wave_min_u32_bcast(unsigned v) {
    int x = (int)v, t;
#define MINSTEP(ctrl, rmask)                                              \
    t = __builtin_amdgcn_update_dpp(-1, x, ctrl, rmask, 0xF, false);      \
    x = ((unsigned)t < (unsigned)x) ? t : x;
    MINSTEP(0x111, 0xF) MINSTEP(0x112, 0xF) MINSTEP(0x114, 0xF)
    MINSTEP(0x118, 0xF) MINSTEP(0x142, 0xA) MINSTEP(0x143, 0xC)
#undef MINSTEP
    return (unsigned)__builtin_amdgcn_readlane(x, 63);
}

// ---------------------------------------------------------------------------
// Exact top-64-smallest selection by (d2, idx) over cnt candidates in LDS,
// restricted to entries with d2 <= r2lim (caller guarantees #passing > 64).
// Radix-select on the d2 bit pattern, 8 bits/round, idx tie-break.
// Produces the same SET as 64 iterations of successor-min. Writes 64 indices.
// ---------------------------------------------------------------------------
DEV void topk64_radix(const float* __restrict__ cD, const int* __restrict__ cI,
                      int cnt, float r2lim, int* buckets, int* nbr, int lane) {
    unsigned prefix = 0;
    int need = 64;
    int shift;
    int done_le_shift = -1;
    for (shift = 24; shift >= 0; shift -= 8) {
        for (int i = lane; i < 256; i += 64) buckets[i] = 0;
        wave_lds_sync();
        for (int e = lane; e < cnt; e += 64) {
            float dv = cD[e];
            if (dv > r2lim) continue;
            unsigned db = __float_as_uint(dv);
            bool match = (shift == 24) || ((db >> (shift + 8)) == prefix);
            if (match) atomicAdd(&buckets[(db >> shift) & 255], 1);
        }
        wave_lds_sync();
        int c0 = buckets[4 * lane + 0], c1 = buckets[4 * lane + 1];
        int c2 = buckets[4 * lane + 2], c3 = buckets[4 * lane + 3];
        int lsum = c0 + c1 + c2 + c3;
        int excl = wave_incl_scan_i32(lsum) - lsum;
        unsigned packed = 0xFFFFFFFFu;
        int cum = excl;
        int cc[4] = {c0, c1, c2, c3};
#pragma unroll
        for (int j = 0; j < 4; j++) {
            if (cum < need && need <= cum + cc[j])
                packed = ((unsigned)(4 * lane + j) << 20) | (unsigned)cum;
            cum += cc[j];
        }
        unsigned win = wave_min_u32_bcast(packed);
        int B = (int)(win >> 20);
        int bef = (int)(win & 0xFFFFF);
        need -= bef;
        prefix = (shift == 24) ? (unsigned)B : ((prefix << 8) | (unsigned)B);
        int cntB = buckets[B];
        if (cntB == need) { done_le_shift = shift; break; }
    }
    int base = 0;
    if (done_le_shift >= 0) {
        int s = done_le_shift;
        unsigned Pv = prefix;
        for (int e0 = 0; e0 < cnt; e0 += 64) {
            int e = e0 + lane;
            bool sel = false;
            if (e < cnt) sel = (cD[e] <= r2lim) && ((__float_as_uint(cD[e]) >> s) <= Pv);
            unsigned long long mk = __ballot(sel);
            int pre = __popcll(mk & ((1ull << lane) - 1ull));
            if (sel) nbr[base + pre] = cI[e];
            base += __popcll(mk);
        }
    } else {
        unsigned T = prefix;
        for (int e0 = 0; e0 < cnt; e0 += 64) {
            int e = e0 + lane;
            bool sel = false;
            if (e < cnt) sel = (cD[e] <= r2lim) && (__float_as_uint(cD[e]) < T);
            unsigned long long mk = __ballot(sel);
            int pre = __popcll(mk & ((1ull << lane) - 1ull));
            if (sel) nbr[base + pre] = cI[e];
            base += __popcll(mk);
        }
        int lastIdx = -1;
        for (int k = 0; k < need; k++) {
            unsigned best = 0xFFFFFFFFu;
            for (int e = lane; e < cnt; e += 64) {
                if (cD[e] <= r2lim && __float_as_uint(cD[e]) == T) {
                    int ix = cI[e];
                    if (ix > lastIdx && (unsigned)ix < best) best = (unsigned)ix;
                }
            }
            best = wave_min_u32_bcast(best);
            if (lane == 0) nbr[base + k] = (int)best;
            lastIdx = (int)best;
        }
    }
}

// ---------------------------------------------------------------------------
// FPS body. One block per batch. PUB: publish progress every 64 steps.
// ---------------------------------------------------------------------------
template<int N, int M, int TPB, bool PUB>
DEV void fps_body(const float* __restrict__ P, float* __restrict__ Q,
                  float* sP, unsigned long long* skey, int* prog) {
    constexpr int PPT = N / TPB;
    constexpr int NW = TPB / 64;
    const int tid = threadIdx.x;
    const int w = tid >> 6;
    const int lane = tid & 63;

    for (int e = tid; e < N * 3; e += TPB) sP[e] = P[e];
    __syncthreads();

    float px[PPT], py[PPT], pz[PPT], mind[PPT];
#pragma unroll
    for (int p = 0; p < PPT; p++) {
        int i = tid + p * TPB;
        px[p] = sP[3 * i]; py[p] = sP[3 * i + 1]; pz[p] = sP[3 * i + 2];
        mind[p] = __builtin_inff();
    }
    float cx = sP[0], cy = sP[1], cz = sP[2];
    if (tid == 0) { Q[0] = cx; Q[1] = cy; Q[2] = cz; }

    for (int s = 1; s < M; s++) {
        float bestm = -1.f;
        int bidx = 0;
#pragma unroll
        for (int p = 0; p < PPT; p++) {
            float d = d2_exact(px[p], py[p], pz[p], cx, cy, cz);
            float m = fminf(mind[p], d);
            mind[p] = m;
            if (m > bestm) { bestm = m; bidx = tid + p * TPB; }  // strict > keeps smallest idx
        }
        unsigned long long key =
            ((unsigned long long)__float_as_uint(bestm) << 32) | (unsigned)(0x7FFFFFFF - bidx);
        key = wave_red_u64_l63<true>(key);
        if (lane == 63) skey[(s & 1) * NW + w] = key;
        __syncthreads();
        const ulonglong2* kv = (const ulonglong2*)(skey + (s & 1) * NW);
        unsigned long long kk = 0ull;
#pragma unroll
        for (int i = 0; i < NW / 2; i++) {
            ulonglong2 v = kv[i];
            unsigned long long m2 = (v.x > v.y) ? v.x : v.y;
            kk = (m2 > kk) ? m2 : kk;
        }
        int sel = 0x7FFFFFFF - (int)(unsigned)(kk & 0xFFFFFFFFu);
        cx = sP[3 * sel]; cy = sP[3 * sel + 1]; cz = sP[3 * sel + 2];
        if (tid == 0) {
            Q[3 * s] = cx; Q[3 * s + 1] = cy; Q[3 * s + 2] = cz;
            if (PUB && ((s + 1) & 63) == 0) {
                __threadfence();          // write back Q before publishing
                atomicAdd(prog, 64);
            }
        }
    }
}

// ---------------------------------------------------------------------------
// Kernel B: blocks 0..3 = FPS1 (publishing progress); blocks 4..515 = SA1
// streaming on published queries. Wave gw: b = gw>>9, x = gw&511; handles
// q = j*512+x for j=0..3, BOTH radii per q with ONE shared distance sweep.
// All 516 blocks co-resident (LDS 49.2KB -> 3 blocks/CU) => spin-safe.
// ---------------------------------------------------------------------------
#define SA1_CAP 1024

struct Sa1Lds {
    float candD[4][SA1_CAP];
    int   candI[4][SA1_CAP];
    int   nbrS[4][64];
    int   buckets[4][256];
    float vbuf[4][64][8];
    float h1buf[4][64];
};
struct Fps1Lds {
    float sP[4096 * 3];
    unsigned long long skey[2 * 4];
};
union BLds { Sa1Lds sa; Fps1Lds fps; };

__global__ __launch_bounds__(256)
void fps1_sa1_kernel(const float* __restrict__ pos, const float* __restrict__ color,
                     float* __restrict__ qpos1,
                     const float* __restrict__ w1, const float* __restrict__ b1,
                     const float* __restrict__ g1, const float* __restrict__ be1,
                     const float* __restrict__ w2, const float* __restrict__ b2,
                     const float* __restrict__ g2, const float* __restrict__ be2,
                     float* __restrict__ x1, int* __restrict__ prog1) {
    __shared__ __align__(16) BLds u;
    const int lane = threadIdx.x & 63;
    const int w = threadIdx.x >> 6;

    if (blockIdx.x < 4) {
        const int b = blockIdx.x;
        fps_body<4096, 2048, 256, true>(pos + (size_t)b * 4096 * 3,
                                        qpos1 + (size_t)b * 2048 * 3,
                                        u.fps.sP, u.fps.skey, &prog1[b]);
        return;
    }

    // ---- SA1 ----
    float w1c[6];
#pragma unroll
    for (int i = 0; i < 6; i++) w1c[i] = w1[i * 64 + lane];
    float w2c[64];
#pragma unroll
    for (int i = 0; i < 64; i++) w2c[i] = w2[i * 64 + lane];
    const float rsc = rsqrtf(1.0f + 1e-5f);
    const float b1f = b1[lane], s1f = g1[lane] * rsc, be1f = be1[lane];
    const float b2f = b2[lane], s2f = g2[lane] * rsc, be2f = be2[lane];

    const int sblk = blockIdx.x - 4;
    const int gw = sblk * 4 + w;        // 0..2047
    const int b = gw >> 9;              // batch
    const int x = gw & 511;

    float* candD_ = u.sa.candD[w];
    int*   candI_ = u.sa.candI[w];
    int*   nbrS_  = u.sa.nbrS[w];
    int*   buckets_ = u.sa.buckets[w];
    float (*vbuf_)[8] = u.sa.vbuf[w];
    float* h1buf_ = u.sa.h1buf[w];

    const float r2a = (float)(0.2 * 0.2);
    const float r2b = (float)(0.1 * 0.1);
    const float* P = pos + (size_t)b * 4096 * 3;
    const float* C = color + (size_t)b * 4096 * 3;

#define SA1_MLP(NV, DSTPTR, QX, QY, QZ)                                                   \
    do {                                                                                  \
        if (lane < (NV)) {                                                                \
            int jj = nbrS_[lane];                                                         \
            vbuf_[lane][0] = C[3 * jj];                                                   \
            vbuf_[lane][1] = C[3 * jj + 1];                                               \
            vbuf_[lane][2] = C[3 * jj + 2];                                               \
            vbuf_[lane][3] = P[3 * jj] - (QX);                                            \
            vbuf_[lane][4] = P[3 * jj + 1] - (QY);                                        \
            vbuf_[lane][5] = P[3 * jj + 2] - (QZ);                                        \
        }                                                                                 \
        wave_lds_sync();                                                                  \
        float mmx = -__builtin_inff();                                                    \
        for (int n = 0; n < (NV); n++) {                                                  \
            float4 v0 = *reinterpret_cast<const float4*>(&vbuf_[n][0]);                   \
            float4 v1 = *reinterpret_cast<const float4*>(&vbuf_[n][4]);                   \
            float h = b1f;                                                                \
            h = fmaf(v0.x, w1c[0], h); h = fmaf(v0.y, w1c[1], h);                         \
            h = fmaf(v0.z, w1c[2], h); h = fmaf(v0.w, w1c[3], h);                         \
            h = fmaf(v1.x, w1c[4], h); h = fmaf(v1.y, w1c[5], h);                         \
            h = fmaxf(h, 0.f);                                                            \
            h = fmaf(h, s1f, be1f);                                                       \
            h1buf_[lane] = h;                                                             \
            wave_lds_sync();                                                              \
            float a = b2f;                                                                \
            _Pragma("unroll")                                                             \
            for (int i4 = 0; i4 < 16; i4++) {                                             \
                float4 hv = *reinterpret_cast<const float4*>(&h1buf_[i4 * 4]);            \
                a = fmaf(hv.x, w2c[4 * i4 + 0], a);                                       \
                a = fmaf(hv.y, w2c[4 * i4 + 1], a);                                       \
                a = fmaf(hv.z, w2c[4 * i4 + 2], a);                                       \
                a = fmaf(hv.w, w2c[4 * i4 + 3], a);                                       \
            }                                                                             \
            a = fmaxf(a, 0.f);                                                            \
            a = fmaf(a, s2f, be2f);                                                       \
            mmx = fmaxf(mmx, a);                                                          \
            __builtin_amdgcn_wave_barrier();                                              \
        }                                                                                 \
        (DSTPTR)[lane] = ((NV) > 0) ? mmx : 0.f;                                          \
    } while (0)

    for (int j = 0; j < 4; j++) {
        int q = j * 512 + x;
        wait_prog(&prog1[b], q + 1);

        float qx, qy, qz;
        {
            int v0 = 0, v1 = 0, v2 = 0;
            if (lane == 0) {
                int* qp = (int*)(qpos1 + ((size_t)b * 2048 + q) * 3);
                v0 = atomicAdd(&qp[0], 0);
                v1 = atomicAdd(&qp[1], 0);
                v2 = atomicAdd(&qp[2], 0);
            }
            qx = __int_as_float(__shfl(v0, 0));
            qy = __int_as_float(__shfl(v1, 0));
            qz = __int_as_float(__shfl(v2, 0));
        }

        // one sweep for both radii (outer r=0.2)
        int cnt0 = 0;
        for (int c0 = 0; c0 < 4096; c0 += 64) {
            int jj = c0 + lane;
            float d2 = d2_exact(P[3 * jj], P[3 * jj + 1], P[3 * jj + 2], qx, qy, qz);
            bool pr = (d2 <= r2a);
            unsigned long long mk = __ballot(pr);
            int pre = __popcll(mk & ((1ull << lane) - 1ull));
            int dst = cnt0 + pre;
            if (pr && dst < SA1_CAP) { candD_[dst] = d2; candI_[dst] = jj; }
            cnt0 += __popcll(mk);
        }
        wave_lds_sync();

        if (cnt0 <= SA1_CAP) {
            // ---- rad 0 (r=0.2) ----
            int nV0;
            if (cnt0 <= 64) {
                nV0 = cnt0;
                if (lane < cnt0) nbrS_[lane] = candI_[lane];
            } else {
                nV0 = 64;
                topk64_radix(candD_, candI_, cnt0, __builtin_inff(), buckets_, nbrS_, lane);
            }
            wave_lds_sync();
            SA1_MLP(nV0, &x1[((size_t)b * 2048 + q) * 128 + 0 * 64], qx, qy, qz);

            // ---- rad 1 (r=0.1): subset of the stored list ----
            int cnt1 = 0;
            for (int e0 = 0; e0 < cnt0; e0 += 64) {
                int e = e0 + lane;
                bool pr = (e < cnt0) && (candD_[e] <= r2b);
                cnt1 += __popcll(__ballot(pr));
            }
            int nV1;
            if (cnt1 <= 64) {
                nV1 = cnt1;
                int basec = 0;
                for (int e0 = 0; e0 < cnt0; e0 += 64) {
                    int e = e0 + lane;
                    bool pr = (e < cnt0) && (candD_[e] <= r2b);
                    unsigned long long mk = __ballot(pr);
                    int pre = __popcll(mk & ((1ull << lane) - 1ull));
                    if (pr) nbrS_[basec + pre] = candI_[e];
                    basec += __popcll(mk);
                }
            } else {
                nV1 = 64;
                topk64_radix(candD_, candI_, cnt0, r2b, buckets_, nbrS_, lane);
            }
            wave_lds_sync();
            SA1_MLP(nV1, &x1[((size_t)b * 2048 + q) * 128 + 1 * 64], qx, qy, qz);
        } else {
            // robust fallback (never expected): serial successor-min per radius
            for (int rad = 0; rad < 2; rad++) {
                float r2 = (rad == 0) ? r2a : r2b;
                int cntR = 0;
                for (int c0 = 0; c0 < 4096; c0 += 64) {
                    int jj = c0 + lane;
                    float d2 = d2_exact(P[3 * jj], P[3 * jj + 1], P[3 * jj + 2], qx, qy, qz);
                    cntR += __popcll(__ballot(d2 <= r2));
                }
                int nV = (cntR < 64) ? cntR : 64;
                unsigned long long lastK = 0ull;
                for (int k = 0; k < nV; k++) {
                    unsigned long long bk = ~0ull;
                    for (int jj = lane; jj < 4096; jj += 64) {
                        float d2 = d2_exact(P[3 * jj], P[3 * jj + 1], P[3 * jj + 2], qx, qy, qz);
                        if (d2 <= r2) {
                            unsigned long long ke =
                                ((unsigned long long)__float_as_uint(d2) << 32) | (unsigned)(jj + 1);
                            if (ke > lastK && ke < bk) bk = ke;
                        }
                    }
                    bk = wave_red_u64_l63<false>(bk);
                    bk = bcast_l63(bk);
                    if (lane == 0) nbrS_[k] = (int)(unsigned)(bk & 0xFFFFFFFFu) - 1;
                    lastK = bk;
                }
                wave_lds_sync();
                SA1_MLP(nV, &x1[((size_t)b * 2048 + q) * 128 + rad * 64], qx, qy, qz);
            }
        }
    }
#undef SA1_MLP
}

// ---------------------------------------------------------------------------
// Kernel C: blocks 0..3 = FPS2 (qpos1 -> qpos2), blocks 4..515 = ypre.
// Independent work, no synchronization.
// ---------------------------------------------------------------------------
struct Fps2Lds {
    float sP[2048 * 3];
    unsigned long long skey[2 * 4];
};
struct YpreLds { float xr[4][4][128]; };
union CLds { Fps2Lds fps; YpreLds yp; };

__global__ __launch_bounds__(256)
void fps2_ypre_kernel(const float* __restrict__ qpos1, float* __restrict__ qpos2,
                      const float* __restrict__ x1, const float* __restrict__ w2a,
                      const float* __restrict__ b2a, float* __restrict__ y) {
    __shared__ __align__(16) CLds u;
    const int lane = threadIdx.x & 63;
    const int w = threadIdx.x >> 6;

    if (blockIdx.x < 4) {
        const int b = blockIdx.x;
        fps_body<2048, 410, 256, false>(qpos1 + (size_t)b * 2048 * 3,
                                        qpos2 + (size_t)b * 410 * 3,
                                        u.fps.sP, u.fps.skey, nullptr);
        return;
    }

    int r0 = ((blockIdx.x - 4) * 4 + w) * 4;  // rows 0..8191, 4 per wave
#pragma unroll
    for (int rr = 0; rr < 4; rr++) {
        const float* X = x1 + (size_t)(r0 + rr) * 128;
        u.yp.xr[w][rr][lane] = X[lane];
        u.yp.xr[w][rr][lane + 64] = X[lane + 64];
    }
    wave_lds_sync();
    float acc[4][2];
#pragma unroll
    for (int rr = 0; rr < 4; rr++) { acc[rr][0] = b2a[lane]; acc[rr][1] = b2a[lane + 64]; }
    for (int i = 0; i < 128; i++) {
        float w0 = w2a[i * 128 + lane];
        float w1v = w2a[i * 128 + 64 + lane];
#pragma unroll
        for (int rr = 0; rr < 4; rr++) {
            float xv = u.yp.xr[w][rr][i];
            acc[rr][0] = fmaf(xv, w0, acc[rr][0]);
            acc[rr][1] = fmaf(xv, w1v, acc[rr][1]);
        }
    }
#pragma unroll
    for (int rr = 0; rr < 4; rr++) {
        y[(size_t)(r0 + rr) * 128 + lane] = acc[rr][0];
        y[(size_t)(r0 + rr) * 128 + 64 + lane] = acc[rr][1];
    }
}

// ---------------------------------------------------------------------------
// SA2 neighbor selection (src = qpos1 [2048], queries = qpos2 [410], 2 radii)
// ---------------------------------------------------------------------------
struct S2Lds {
    float cD[4][2048];
    int   cI[4][2048];
    int   buckets[4][256];
};

__global__ __launch_bounds__(256)
void sa2sel_kernel(const float* __restrict__ qpos1, const float* __restrict__ qpos2,
                   int* __restrict__ cntOut, int* __restrict__ nbrOut) {
    __shared__ __align__(16) S2Lds u;
    const int lane = threadIdx.x & 63;
    const int w = threadIdx.x >> 6;
    int p = blockIdx.x * 4 + w;  // 0..3279
    int rad = p & 1;
    int q = (p >> 1) % 410;
    int b = (p >> 1) / 410;
    float r2 = (rad == 0) ? (float)(0.35 * 0.35) : 0.25f;
    const float* S = qpos1 + (size_t)b * 2048 * 3;
    const float* QP = qpos2 + ((size_t)b * 410 + q) * 3;
    float qx = QP[0], qy = QP[1], qz = QP[2];

    int cnt = 0;
    for (int c0 = 0; c0 < 2048; c0 += 64) {
        int j = c0 + lane;
        float d2 = d2_exact(S[3 * j], S[3 * j + 1], S[3 * j + 2], qx, qy, qz);
        bool pr = (d2 <= r2);
        unsigned long long mk = __ballot(pr);
        int pre = __popcll(mk & ((1ull << lane) - 1ull));
        if (pr) { u.cD[w][cnt + pre] = d2; u.cI[w][cnt + pre] = j; }
        cnt += __popcll(mk);
    }
    wave_lds_sync();

    int nV = (cnt < 64) ? cnt : 64;
    if (cnt <= 64) {
        if (lane < cnt) nbrOut[(size_t)p * 64 + lane] = u.cI[w][lane];
    } else {
        topk64_radix(u.cD[w], u.cI[w], cnt, __builtin_inff(),
                     u.buckets[w], nbrOut + (size_t)p * 64, lane);
    }
    if (lane == 0) cntOut[p] = nV;
}

// ---------------------------------------------------------------------------
// SA2 PointConv: per (b,q,rad) block: h1 (128) for <=64 neighbors, then
// [64x128]@[128x256] f32 GEMM, ReLU/BN, masked max -> A3 row (520 cols).
// ---------------------------------------------------------------------------
__global__ __launch_bounds__(256)
void sa2gemm_kernel(const float* __restrict__ y, const float* __restrict__ qpos1,
                    const float* __restrict__ qpos2, const float* __restrict__ w2a,
                    const float* __restrict__ g2a, const float* __restrict__ be2a,
                    const float* __restrict__ w2b, const float* __restrict__ b2b,
                    const float* __restrict__ g2b, const float* __restrict__ be2b,
                    const int* __restrict__ cntIn, const int* __restrict__ nbrIn,
                    float* __restrict__ A3) {
    __shared__ __align__(16) float h1T[128][68];
    __shared__ __align__(16) float Bs[16][256];
    __shared__ int nbrS[64];

    const int tid = threadIdx.x;
    const int lane = tid & 63;
    const int w = tid >> 6;
    int p = blockIdx.x;
    int rad = p & 1;
    int q = (p >> 1) % 410;
    int b = (p >> 1) / 410;
    int nV = cntIn[p];
    if (tid < 64) nbrS[tid] = nbrIn[(size_t)p * 64 + tid];
    __syncthreads();

    const float* QP = qpos2 + ((size_t)b * 410 + q) * 3;
    float qx = QP[0], qy = QP[1], qz = QP[2];
    const float rs = rsqrtf(1.0f + 1e-5f);
    float wr0a = w2a[128 * 128 + lane], wr1a = w2a[129 * 128 + lane], wr2a = w2a[130 * 128 + lane];
    float wr0b = w2a[128 * 128 + 64 + lane], wr1b = w2a[129 * 128 + 64 + lane], wr2b = w2a[130 * 128 + 64 + lane];
    float sA = g2a[lane] * rs, beA = be2a[lane];
    float sB = g2a[64 + lane] * rs, beB = be2a[64 + lane];

    for (int n = w; n < 64; n += 4) {
        float v0 = 0.f, v1 = 0.f;
        if (n < nV) {
            int j = nbrS[n];
            const float* Y = y + ((size_t)b * 2048 + j) * 128;
            const float* S = qpos1 + ((size_t)b * 2048 + j) * 3;
            float rx = S[0] - qx, ry = S[1] - qy, rz = S[2] - qz;
            float p0 = Y[lane];
            p0 = fmaf(rx, wr0a, p0); p0 = fmaf(ry, wr1a, p0); p0 = fmaf(rz, wr2a, p0);
            float p1 = Y[64 + lane];
            p1 = fmaf(rx, wr0b, p1); p1 = fmaf(ry, wr1b, p1); p1 = fmaf(rz, wr2b, p1);
            v0 = fmaf(fmaxf(p0, 0.f), sA, beA);
            v1 = fmaf(fmaxf(p1, 0.f), sB, beB);
        }
        h1T[lane][n] = v0;
        h1T[64 + lane][n] = v1;
    }
    __syncthreads();

    const int tn = tid & 7;        // neighbor octet
    const int tf = tid >> 3;       // 0..31 -> 8 output cols each
    float acc[8][8];
#pragma unroll
    for (int r = 0; r < 8; r++)
#pragma unroll
        for (int c = 0; c < 8; c++) acc[r][c] = 0.f;

    for (int kt = 0; kt < 8; kt++) {
        __syncthreads();
#pragma unroll
        for (int i = 0; i < 16; i++) {
            int ee = tid + 256 * i;
            int r = ee >> 8, c = ee & 255;
            Bs[r][c] = w2b[(kt * 16 + r) * 256 + c];
        }
        __syncthreads();
#pragma unroll
        for (int kk = 0; kk < 16; kk++) {
            float4 a0 = *reinterpret_cast<const float4*>(&h1T[kt * 16 + kk][tn * 8]);
            float4 a1 = *reinterpret_cast<const float4*>(&h1T[kt * 16 + kk][tn * 8 + 4]);
            float4 b0 = *reinterpret_cast<const float4*>(&Bs[kk][tf * 8]);
            float4 b1 = *reinterpret_cast<const float4*>(&Bs[kk][tf * 8 + 4]);
            float av[8] = {a0.x, a0.y, a0.z, a0.w, a1.x, a1.y, a1.z, a1.w};
            float bv[8] = {b0.x, b0.y, b0.z, b0.w, b1.x, b1.y, b1.z, b1.w};
#pragma unroll
            for (int r = 0; r < 8; r++)
#pragma unroll
                for (int c = 0; c < 8; c++) acc[r][c] = fmaf(av[r], bv[c], acc[r][c]);
        }
    }

    const int f2 = tf * 8;
    float bb[8], ss[8], beb[8];
#pragma unroll
    for (int c = 0; c < 8; c++) {
        bb[c] = b2b[f2 + c];
        ss[c] = g2b[f2 + c] * rs;
        beb[c] = be2b[f2 + c];
    }
    float mx[8];
#pragma unroll
    for (int c = 0; c < 8; c++) mx[c] = -__builtin_inff();
#pragma unroll
    for (int r = 0; r < 8; r++) {
        int n = tn * 8 + r;
        bool val = (n < nV);
#pragma unroll
        for (int c = 0; c < 8; c++) {
            float h = fmaf(fmaxf(acc[r][c] + bb[c], 0.f), ss[c], beb[c]);
            if (val) mx[c] = fmaxf(mx[c], h);
        }
    }
#pragma unroll
    for (int off = 1; off < 8; off <<= 1) {
#pragma unroll
        for (int c = 0; c < 8; c++) {
            float o = __shfl_xor(mx[c], off);
            mx[c] = fmaxf(mx[c], o);
        }
    }
    if (tn == 0) {
        size_t row3 = (size_t)b * 410 + q;
        float* dst = A3 + row3 * 520 + rad * 256 + f2;
#pragma unroll
        for (int c = 0; c < 8; c++) dst[c] = (nV > 0) ? mx[c] : 0.f;
    }
    if (rad == 0 && tid < 3) {
        A3[((size_t)b * 410 + q) * 520 + 512 + tid] = QP[tid];
    }
}

// ---------------------------------------------------------------------------
// Layer3 GEMM [410x515]@[515x1024] + ReLU/BN + row-max into g[4][1024]
// ---------------------------------------------------------------------------
__global__ __launch_bounds__(256)
void l3_kernel(const float* __restrict__ A3, const float* __restrict__ w3,
               const float* __restrict__ b3, const float* __restrict__ g3,
               const float* __restrict__ be3, float* __restrict__ gout) {
    __shared__ float As[32][17];
    __shared__ float Bs[16][256];
    __shared__ float pm[4][256];
    const int tid = threadIdx.x;
    const int rt = blockIdx.x;   // 0..12
    const int ct = blockIdx.y;   // 0..3
    const int b = blockIdx.z;
    const int rgrp = tid >> 6, li = tid & 63;

    float acc[8][4];
#pragma unroll
    for (int r = 0; r < 8; r++)
#pragma unroll
        for (int j = 0; j < 4; j++) acc[r][j] = 0.f;

    for (int kt = 0; kt < 33; kt++) {
        __syncthreads();
        for (int e = tid; e < 512; e += 256) {
            int r = e >> 4, kk = e & 15;
            int row = rt * 32 + r;
            int k = kt * 16 + kk;
            As[r][kk] = (row < 410 && k < 515) ? A3[((size_t)b * 410 + row) * 520 + k] : 0.f;
        }
        for (int e = tid; e < 4096; e += 256) {
            int r = e >> 8, c = e & 255;
            int k = kt * 16 + r;
            Bs[r][c] = (k < 515) ? w3[(size_t)k * 1024 + ct * 256 + c] : 0.f;
        }
        __syncthreads();
#pragma unroll
        for (int kk = 0; kk < 16; kk++) {
            float bvv[4];
#pragma unroll
            for (int j = 0; j < 4; j++) bvv[j] = Bs[kk][li + 64 * j];
#pragma unroll
            for (int r = 0; r < 8; r++) {
                float av = As[rgrp * 8 + r][kk];
#pragma unroll
                for (int j = 0; j < 4; j++) acc[r][j] = fmaf(av, bvv[j], acc[r][j]);
            }
        }
    }

    const float rs = rsqrtf(1.0f + 1e-5f);
    float mx[4], bb[4], ss[4], beb[4];
#pragma unroll
    for (int j = 0; j < 4; j++) {
        int c = ct * 256 + li + 64 * j;
        bb[j] = b3[c]; ss[j] = g3[c] * rs; beb[j] = be3[c];
        mx[j] = -__builtin_inff();
    }
#pragma unroll
    for (int r = 0; r < 8; r++) {
        int row = rt * 32 + rgrp * 8 + r;
        bool val = (row < 410);
#pragma unroll
        for (int j = 0; j < 4; j++) {
            float h = fmaf(fmaxf(acc[r][j] + bb[j], 0.f), ss[j], beb[j]);
            if (val) mx[j] = fmaxf(mx[j], h);
        }
    }
#pragma unroll
    for (int j = 0; j < 4; j++) pm[rgrp][li + 64 * j] = mx[j];
    __syncthreads();
    if (rgrp == 0) {
#pragma unroll
        for (int j = 0; j < 4; j++) {
            int c = li + 64 * j;
            float v = fmaxf(fmaxf(pm[0][c], pm[1][c]), fmaxf(pm[2][c], pm[3][c]));
            atomicMaxF(&gout[b * 1024 + ct * 256 + c], v);
        }
    }
}

// init: gbuf = -inf, prog1 = 0
__global__ __launch_bounds__(256)
void init_kernel(float* g, int* prog1) {
    int i = blockIdx.x * 256 + threadIdx.x;
    if (i < 4096) g[i] = -__builtin_inff();
    if (i < 4) prog1[i] = 0;
}

// ---------------------------------------------------------------------------
// Head: relu(g@wl1+bl1) @ wl2 + bl2, L2-normalize rows -> out [4,128]
// ---------------------------------------------------------------------------
__global__ __launch_bounds__(512)
void head_kernel(const float* __restrict__ g, const float* __restrict__ wl1,
                 const float* __restrict__ bl1, const float* __restrict__ wl2,
                 const float* __restrict__ bl2, float* __restrict__ out) {
    __shared__ float gs[1024];
    __shared__ float h1s[512];
    __shared__ float ov[128];
    __shared__ float nrm;
    const int b = blockIdx.x, tid = threadIdx.x;
    gs[tid] = g[b * 1024 + tid];
    gs[tid + 512] = g[b * 1024 + 512 + tid];
    __syncthreads();
    float a = bl1[tid];
#pragma unroll 4
    for (int i = 0; i < 1024; i++) a = fmaf(gs[i], wl1[i * 512 + tid], a);
    h1s[tid] = fmaxf(a, 0.f);
    __syncthreads();
    if (tid < 128) {
        float a2 = bl2[tid];
        for (int i = 0; i < 512; i++) a2 = fmaf(h1s[i], wl2[i * 128 + tid], a2);
        ov[tid] = a2;
    }
    __syncthreads();
    if (tid == 0) {
        float ssum = 0.f;
        for (int i = 0; i < 128; i++) ssum += ov[i] * ov[i];
        nrm = sqrtf(ssum);
    }
    __syncthreads();
    if (tid < 128) out[b * 128 + tid] = ov[tid] / nrm;
}

// ---------------------------------------------------------------------------
extern "C" void kernel_launch(void* const* d_in, const int* in_sizes, int n_in,
                              void* d_out, int out_size, void* d_ws, size_t ws_size,
                              hipStream_t stream) {
    const float* xyz   = (const float*)d_in[0];
    const float* color = (const float*)d_in[1];
    const float* w1a = (const float*)d_in[2];
    const float* b1a = (const float*)d_in[3];
    const float* g1a = (const float*)d_in[4];
    const float* be1a = (const float*)d_in[5];
    const float* w1b = (const float*)d_in[6];
    const float* b1b = (const float*)d_in[7];
    const float* g1b = (const float*)d_in[8];
    const float* be1b = (const float*)d_in[9];
    const float* w2a = (const float*)d_in[10];
    const float* b2a = (const float*)d_in[11];
    const float* g2a = (const float*)d_in[12];
    const float* be2a = (const float*)d_in[13];
    const float* w2b = (const float*)d_in[14];
    const float* b2b = (const float*)d_in[15];
    const float* g2b = (const float*)d_in[16];
    const float* be2b = (const float*)d_in[17];
    const float* w3 = (const float*)d_in[18];
    const float* b3 = (const float*)d_in[19];
    const float* g3 = (const float*)d_in[20];
    const float* be3 = (const float*)d_in[21];
    const float* wl1 = (const float*)d_in[22];
    const float* bl1 = (const float*)d_in[23];
    const float* wl2 = (const float*)d_in[24];
    const float* bl2 = (const float*)d_in[25];
    float* out = (float*)d_out;

    // workspace carve-up (floats)
    float* W = (float*)d_ws;
    float* qpos1 = W;                       // 4*2048*3   = 24576
    float* qpos2 = qpos1 + 24576;           // 4*410*3    = 4920 -> pad 4928
    float* x1    = qpos2 + 4928;            // 4*2048*128 = 1048576
    float* ybuf  = x1 + 1048576;            // 4*2048*128 = 1048576
    float* A3    = ybuf + 1048576;          // 1640*520   = 852800
    float* gbuf  = A3 + 852800;             // 4096
    int* cntBuf  = (int*)(gbuf + 4096);     // 3280
    int* nbrBuf  = cntBuf + 3280;           // 3280*64 = 209920
    int* prog1   = nbrBuf + 209920;         // 4 (+pad)

    init_kernel<<<16, 256, 0, stream>>>(gbuf, prog1);
    fps1_sa1_kernel<<<516, 256, 0, stream>>>(xyz, color, qpos1,
                                             w1a, b1a, g1a, be1a,
                                             w1b, b1b, g1b, be1b, x1, prog1);
    fps2_ypre_kernel<<<516, 256, 0, stream>>>(qpos1, qpos2, x1, w2a, b2a, ybuf);
    sa2sel_kernel<<<820, 256, 0, stream>>>(qpos1, qpos2, cntBuf, nbrBuf);
    sa2gemm_kernel<<<3280, 256, 0, stream>>>(ybuf, qpos1, qpos2, w2a, g2a, be2a,
                                             w2b, b2b, g2b, be2b, cntBuf, nbrBuf, A3);
    l3_kernel<<<dim3(13, 4, 4), 256, 0, stream>>>(A3, w3, b3, g3, be3, gbuf);
    head_kernel<<<4, 512, 0, stream>>>(gbuf, wl1, bl1, wl2, bl2, out);
}